// Round 1
// baseline (739.806 us; speedup 1.0000x reference)
//
#include <hip/hip_runtime.h>
#include <hip/hip_bf16.h>

// CausalMLA: B=2, L=2048, D=2048, H=16, HD=128, LD=32. Inputs fp32 or bf16
// (runtime-detected); pipeline bf16/MFMA; output dtype follows input.
// R4: RoPE+compress fused into QKV-GEMM epilogue.
// R5: algebraic folds — V compress folded into weights (W~v = Wv@Wvc),
//     decompress folded into output weights (W~o = Wd@Wo per head).
//     QKV GEMM N: 6144->4608 (V quarter-width, no epilogue); out-GEMM K: 2048->512;
//     flash32 loses decompress epilogue (writes 512-wide attn, not 2048-wide y).

#define Bsz 2
#define Lseq 2048
#define Dmod 2048
#define Hn 16
#define HDim 128
#define LDim 32

typedef __bf16 bf16x8 __attribute__((ext_vector_type(8)));
typedef float f32x4 __attribute__((ext_vector_type(4)));
typedef __hip_bfloat16 bf16;

#define GLDS16(g, l)                                                    \
  __builtin_amdgcn_global_load_lds(                                     \
      (const __attribute__((address_space(1))) unsigned int*)(g),       \
      (__attribute__((address_space(3))) unsigned int*)(l), 16, 0, 0)

// ---- small-constants area layout (bf16 element offsets inside `small`) ----
#define SM_COS 0
#define SM_SIN 131072
#define SM_WC 262144     // Wqc|Wkc|Wvc 3*4096
#define SM_BC 274432     // bqc|bkc|bvc 3*32
#define SM_WD 274528     // 4096 (row-major Wd[e][hd] — used by fold_ow)
#define SM_BD 278624     // 128
#define SM_BO 278752     // 2048
#define SM_BQKV 280800   // bq|bk|bv 3*2048
#define SM_TOT 286944

// ---------------- dtype detector ----------------
__global__ void detect_dtype(const ushort* __restrict__ x, int* __restrict__ flag) {
  int t = threadIdx.x;  // 64 threads
  int bad = 0;
  for (int k = 0; k < 4; ++k) {
    ushort u = x[t * 4 + k];
    int ex = (u >> 7) & 0xFF;
    if (ex >= 0xC0) bad = 1;
  }
  unsigned long long b = __ballot(bad);
  if (t == 0) *flag = (b != 0ULL) ? 1 : 0;  // 1 = inputs are fp32
}

__device__ inline void conv8(const void* src, size_t so, bf16* dst, size_t dof, int f32) {
  if (f32) {
    const float* s = (const float*)src + so;
    bf16 tmp[8] __attribute__((aligned(16)));
    for (int j = 0; j < 8; ++j) tmp[j] = __float2bfloat16(s[j]);
    *(uint4*)&dst[dof] = *(uint4*)tmp;
  } else {
    *(uint4*)&dst[dof] = *(const uint4*)((const ushort*)src + so);
  }
}

__device__ inline float cv1(const void* s, size_t i, int f32) {
  return f32 ? ((const float*)s)[i] : __bfloat162float(((const bf16*)s)[i]);
}

__global__ __launch_bounds__(256) void conv_x(const void* __restrict__ xs,
                                              bf16* __restrict__ xd,
                                              const int* __restrict__ flagp) {
  int f32 = *flagp;
  size_t e = ((size_t)blockIdx.x * 256 + threadIdx.x) * 8;
  conv8(xs, e, xd, e, f32);
}

// ---------------- prep: small-area conversion + wctG/wdtG ----------------
__global__ __launch_bounds__(256) void prep(
    const void* cosS, const void* sinS, const void* WqcS, const void* WkcS,
    const void* WvcS, const void* bqcS, const void* bkcS, const void* bvcS,
    const void* WdS, const void* bdS, const void* boS, const void* bqS,
    const void* bkS, const void* bvS, bf16* __restrict__ dst,
    bf16* __restrict__ wctG, bf16* __restrict__ wdtG,
    const int* __restrict__ flagp) {
  int f32 = *flagp;
  int tid = blockIdx.x * 256 + threadIdx.x;  // grid 160 -> 40960
  if (tid < SM_TOT / 8) {
    size_t e = (size_t)tid * 8;
    const void* src;
    size_t so;
    if (e < SM_SIN) { src = cosS; so = e - SM_COS; }
    else if (e < SM_WC) { src = sinS; so = e - SM_SIN; }
    else if (e < SM_BC) { size_t r = e - SM_WC; src = (r < 4096) ? WqcS : (r < 8192) ? WkcS : WvcS; so = r & 4095; }
    else if (e < SM_WD) { size_t r = e - SM_BC; src = (r < 32) ? bqcS : (r < 64) ? bkcS : bvcS; so = r & 31; }
    else if (e < SM_BD) { src = WdS; so = e - SM_WD; }
    else if (e < SM_BO) { src = bdS; so = e - SM_BD; }
    else if (e < SM_BQKV) { src = boS; so = e - SM_BO; }
    else { size_t r = e - SM_BQKV; src = (r < 2048) ? bqS : (r < 4096) ? bkS : bvS; so = r & 2047; }
    conv8(src, so, dst, e, f32);
  } else {
    int idx = tid - SM_TOT / 8;
    for (int i = idx; i < 16384; i += 40960 - SM_TOT / 8) {
      if (i < 12288) {
        int reg = i >> 12, rem = i & 4095, n = rem >> 7, k = rem & 127;
        const void* src = (reg == 0) ? WqcS : (reg == 1) ? WkcS : WvcS;
        wctG[i] = __float2bfloat16(cv1(src, (size_t)k * 32 + n, f32));
      } else {
        int i2 = i - 12288, o = i2 >> 5, e = i2 & 31;
        wdtG[i2] = __float2bfloat16(cv1(WdS, (size_t)e * 128 + o, f32));
      }
    }
  }
}

// ---------------- 3 weight transposes: Wt[n][k] = W[k][n] (Wq, Wk, Wo) ----------------
__global__ __launch_bounds__(256) void transpose3(const void* __restrict__ WqS,
                                                  const void* __restrict__ WkS,
                                                  const void* __restrict__ WoS,
                                                  bf16* __restrict__ WtQK,
                                                  bf16* __restrict__ WtO,
                                                  const int* __restrict__ flagp) {
  __shared__ float tile[64][65];
  int f32 = *flagp;
  int z = blockIdx.z;
  const void* W = (z == 0) ? WqS : (z == 1) ? WkS : WoS;
  bf16* Wt = (z == 2) ? WtO : (WtQK + (size_t)z * 2048 * 2048);
  int n0 = blockIdx.x * 64, k0 = blockIdx.y * 64;
  int t = threadIdx.x;
  int x = (t & 7) * 8, y = t >> 3;
  for (int p = 0; p < 2; ++p) {
    int r = y + p * 32;
    if (f32) {
      const float* src = (const float*)W + (size_t)(k0 + r) * 2048 + n0 + x;
      float4 a = *(const float4*)src;
      float4 b2 = *(const float4*)(src + 4);
      tile[r][x + 0] = a.x; tile[r][x + 1] = a.y; tile[r][x + 2] = a.z; tile[r][x + 3] = a.w;
      tile[r][x + 4] = b2.x; tile[r][x + 5] = b2.y; tile[r][x + 6] = b2.z; tile[r][x + 7] = b2.w;
    } else {
      const ushort* src = (const ushort*)W + (size_t)(k0 + r) * 2048 + n0 + x;
      uint4 u = *(const uint4*)src;
      bf16* e = (bf16*)&u;
      for (int j = 0; j < 8; ++j) tile[r][x + j] = __bfloat162float(e[j]);
    }
  }
  __syncthreads();
  for (int p = 0; p < 2; ++p) {
    int n = y + p * 32;
    bf16 tmp[8] __attribute__((aligned(16)));
    for (int j = 0; j < 8; ++j) tmp[j] = __float2bfloat16(tile[x + j][n]);
    *(uint4*)&Wt[(size_t)(n0 + n) * 2048 + k0 + x] = *(uint4*)tmp;
  }
}

// ---------------- fold_vw: W~vt[(h*32+e)][d_in] = sum_hd Wvc^T[e][hd] * Wv[d_in][128h+hd] ----------------
// Per (h, nb): M=32 (e), N=128 (d_in cols), K=128. Direct-to-frag, no LDS.
__global__ __launch_bounds__(256) void fold_vw(const bf16* __restrict__ WvB,
                                               const bf16* __restrict__ wctG,
                                               bf16* __restrict__ Wvt) {
  int nb = blockIdx.x, h = blockIdx.y;
  int t = threadIdx.x, lane = t & 63, w = t >> 6;
  int qd = lane >> 4, ln = lane & 15;
  f32x4 acc[2][2] = {};
  for (int kt = 0; kt < 4; ++kt) {
    bf16x8 af[2], bfr[2];
    for (int i = 0; i < 2; ++i)
      af[i] = *(const bf16x8*)&wctG[8192 + (i * 16 + ln) * 128 + kt * 32 + qd * 8];
    for (int j = 0; j < 2; ++j)
      bfr[j] = *(const bf16x8*)&WvB[(size_t)(nb * 128 + w * 32 + j * 16 + ln) * 2048 +
                                    h * 128 + kt * 32 + qd * 8];
    for (int i = 0; i < 2; ++i)
      for (int j = 0; j < 2; ++j)
        acc[i][j] = __builtin_amdgcn_mfma_f32_16x16x32_bf16(af[i], bfr[j], acc[i][j], 0, 0, 0);
  }
  for (int i = 0; i < 2; ++i)
    for (int j = 0; j < 2; ++j)
      for (int r = 0; r < 4; ++r) {
        int e = i * 16 + qd * 4 + r;
        int col = nb * 128 + w * 32 + j * 16 + ln;
        Wvt[(size_t)(h * 32 + e) * 2048 + col] = __float2bfloat16(acc[i][j][r]);
      }
}

// ---------------- fold_ow: W~ot[d_out][(h*32+e)] = sum_hd Wd[e][hd] * WtO[d_out][128h+hd] ----------------
// Per (h, mb): M=128 (d_out rows), N=32 (e), K=128. Direct-to-frag, no LDS.
__global__ __launch_bounds__(256) void fold_ow(const bf16* __restrict__ WtO,
                                               const bf16* __restrict__ small,
                                               bf16* __restrict__ Wot) {
  int mb = blockIdx.x, h = blockIdx.y;
  int t = threadIdx.x, lane = t & 63, w = t >> 6;
  int qd = lane >> 4, ln = lane & 15;
  f32x4 acc[2][2] = {};
  for (int kt = 0; kt < 4; ++kt) {
    bf16x8 af[2], bfr[2];
    for (int i = 0; i < 2; ++i)
      af[i] = *(const bf16x8*)&WtO[(size_t)(mb * 128 + w * 32 + i * 16 + ln) * 2048 +
                                   h * 128 + kt * 32 + qd * 8];
    for (int j = 0; j < 2; ++j)
      bfr[j] = *(const bf16x8*)&small[SM_WD + (j * 16 + ln) * 128 + kt * 32 + qd * 8];
    for (int i = 0; i < 2; ++i)
      for (int j = 0; j < 2; ++j)
        acc[i][j] = __builtin_amdgcn_mfma_f32_16x16x32_bf16(af[i], bfr[j], acc[i][j], 0, 0, 0);
  }
  for (int i = 0; i < 2; ++i)
    for (int j = 0; j < 2; ++j)
      for (int r = 0; r < 4; ++r) {
        int row = mb * 128 + w * 32 + i * 16 + qd * 4 + r;
        int col = h * 32 + j * 16 + ln;
        Wot[(size_t)row * 512 + col] = __float2bfloat16(acc[i][j][r]);
      }
}

// ---------------- fold_bias: boF = bo + bd_tiled@Wo (fp32); bvF = bv@Wvc(per-head) + bvc ----------------
__global__ __launch_bounds__(256) void fold_bias(const void* boS, const void* bdS,
                                                 const void* WoS, const void* bvS,
                                                 const void* bvcS, const void* WvcS,
                                                 float* __restrict__ boF,
                                                 float* __restrict__ bvF,
                                                 const int* __restrict__ flagp) {
  int f32 = *flagp;
  int tid = blockIdx.x * 256 + threadIdx.x;  // grid 10 -> 2560
  if (tid < 2048) {
    float s = cv1(boS, tid, f32);
    for (int k = 0; k < 2048; ++k)
      s += cv1(bdS, k & 127, f32) * cv1(WoS, (size_t)k * 2048 + tid, f32);
    boF[tid] = s;
  } else if (tid < 2560) {
    int j = tid - 2048, h = j >> 5, e = j & 31;
    float s = cv1(bvcS, e, f32);
    for (int hd = 0; hd < 128; ++hd)
      s += cv1(bvS, h * 128 + hd, f32) * cv1(WvcS, (size_t)hd * 32 + e, f32);
    bvF[j] = s;
  }
}

// ---------------- QKV GEMM: bn<32 = Q|K (fused RoPE+compress); bn>=32 = folded-V -> vcT ----------------
#define ESTR 136
__global__ __launch_bounds__(256) void gemm_qkv_compress(
    const bf16* __restrict__ A, const bf16* __restrict__ Bt,
    const bf16* __restrict__ Wvt, const bf16* __restrict__ small,
    const bf16* __restrict__ wctG, const float* __restrict__ bvF,
    bf16* __restrict__ qc, bf16* __restrict__ kc, bf16* __restrict__ vcT) {
  __shared__ bf16 sh[128 * ESTR];  // 34816 B; first 16KB doubles as lA|lB
  bf16* lA = sh;
  bf16* lB = sh + 4096;
  const int K = 2048;
  int bm = blockIdx.y, bn = blockIdx.x;
  int t = threadIdx.x;
  int lane = t & 63, w = t >> 6;
  int wm = (w >> 1) * 64, wn = (w & 1) * 64;
  int qd = lane >> 4, ln = lane & 15;

  f32x4 acc[4][4] = {};
  const bf16* Ab = A + (size_t)(bm * 128) * K;
  const bf16* Bb = (bn < 32) ? (Bt + (size_t)(bn * 128) * K)
                             : (Wvt + (size_t)((bn - 32) * 128) * K);

  for (int kt = 0; kt < K; kt += 32) {
    for (int p = 0; p < 2; ++p) {
      int slot = t + p * 256;
      int r = slot >> 2, c = (slot & 3) * 8;
      GLDS16(&Ab[(size_t)r * K + kt + c], &lA[slot * 8]);
      GLDS16(&Bb[(size_t)r * K + kt + c], &lB[slot * 8]);
    }
    __syncthreads();
    bf16x8 af[4], bfr[4];
    for (int i = 0; i < 4; ++i) af[i] = *(bf16x8*)&lA[(wm + i * 16 + ln) * 32 + qd * 8];
    for (int j = 0; j < 4; ++j) bfr[j] = *(bf16x8*)&lB[(wn + j * 16 + ln) * 32 + qd * 8];
    for (int i = 0; i < 4; ++i)
      for (int j = 0; j < 4; ++j)
        acc[i][j] = __builtin_amdgcn_mfma_f32_16x16x32_bf16(af[i], bfr[j], acc[i][j], 0, 0, 0);
    __syncthreads();
  }

  if (bn >= 32) {
    // folded-V epilogue: acc + bvF -> vcT[(b*512 + n)][l] (transposed write)
    int bn2 = bn - 32;
    int b = bm >> 4;
    for (int j = 0; j < 4; ++j) {
      int n = bn2 * 128 + wn + j * 16 + ln;
      float bb = bvF[n];
      for (int i = 0; i < 4; ++i) {
        int lbase = (bm & 15) * 128 + wm + i * 16 + qd * 4;
        bf16 p4[4] __attribute__((aligned(8)));
        for (int r = 0; r < 4; ++r) p4[r] = __float2bfloat16(acc[i][j][r] + bb);
        *(uint2*)&vcT[((size_t)(b * 512 + n)) * 2048 + lbase] = *(uint2*)p4;
      }
    }
    return;
  }

  int reg = bn >> 4, h = bn & 15;
  // epilogue 1: acc + bias -> LDS tile (row = block-local l, col = head dim)
  for (int j = 0; j < 4; ++j) {
    int col = wn + j * 16 + ln;
    float bv = __bfloat162float(small[SM_BQKV + bn * 128 + col]);
    for (int i = 0; i < 4; ++i)
      for (int r = 0; r < 4; ++r)
        sh[(wm + i * 16 + qd * 4 + r) * ESTR + col] = __float2bfloat16(acc[i][j][r] + bv);
  }
  __syncthreads();

  // epilogue 2: RoPE + compress 32 l-rows per wave
  int r0 = w * 32;
  int b = bm >> 4;
  int bh = b * Hn + h;
  bf16x8 bfr2[2][4];
  for (int nt = 0; nt < 2; ++nt)
    for (int kt = 0; kt < 4; ++kt)
      bfr2[nt][kt] = *(const bf16x8*)&wctG[reg * 4096 + (nt * 16 + ln) * 128 + kt * 32 + qd * 8];
  float bc[2];
  bc[0] = __bfloat162float(small[SM_BC + reg * 32 + ln]);
  bc[1] = __bfloat162float(small[SM_BC + reg * 32 + 16 + ln]);

  for (int mt = 0; mt < 2; ++mt) {
    int lb = r0 + mt * 16 + ln;
    int lg = (bm & 15) * 128 + lb;
    f32x4 c2[2] = {};
    for (int kt = 0; kt < 4; ++kt) {
      uint4 u = *(uint4*)&sh[lb * ESTR + kt * 32 + qd * 8];
      bf16* e8 = (bf16*)&u;
      int pbase = kt * 16 + qd * 4;
      for (int j = 0; j < 4; ++j) {
        float cvv = __bfloat162float(small[SM_COS + (size_t)lg * 64 + pbase + j]);
        float svv = __bfloat162float(small[SM_SIN + (size_t)lg * 64 + pbase + j]);
        float ev = __bfloat162float(e8[2 * j]);
        float ov = __bfloat162float(e8[2 * j + 1]);
        e8[2 * j] = __float2bfloat16(ev * cvv - ov * svv);
        e8[2 * j + 1] = __float2bfloat16(ev * svv + ov * cvv);
      }
      bf16x8 a = *(bf16x8*)&u;
      c2[0] = __builtin_amdgcn_mfma_f32_16x16x32_bf16(a, bfr2[0][kt], c2[0], 0, 0, 0);
      c2[1] = __builtin_amdgcn_mfma_f32_16x16x32_bf16(a, bfr2[1][kt], c2[1], 0, 0, 0);
    }
    int lgbase = (bm & 15) * 128 + r0 + mt * 16 + qd * 4;
    bf16* dst = (reg == 0) ? qc : kc;
    for (int nt = 0; nt < 2; ++nt)
      for (int r = 0; r < 4; ++r)
        dst[((size_t)bh * Lseq + lgbase + r) * 32 + nt * 16 + ln] =
            __float2bfloat16(c2[nt][r] + bc[nt]);
  }
}

// ---------------- output GEMM: d_out = attn @ Wot^T + boF (fp32 bias), K=512 ----------------
__global__ __launch_bounds__(256) void gemm_bias_out(const bf16* __restrict__ A,
                                                     const bf16* __restrict__ Bt,
                                                     const float* __restrict__ bias,
                                                     void* __restrict__ C,
                                                     int M, int N, int K,
                                                     const int* __restrict__ flagp) {
  __shared__ bf16 lA[128 * 32];
  __shared__ bf16 lB[128 * 32];
  int f32out = *flagp;
  int bm = blockIdx.y, bn = blockIdx.x;
  int t = threadIdx.x;
  int lane = t & 63, w = t >> 6;
  int wm = (w >> 1) * 64, wn = (w & 1) * 64;
  int qd = lane >> 4, ln = lane & 15;

  f32x4 acc[4][4] = {};
  const bf16* Ab = A + (size_t)(bm * 128) * K;
  const bf16* Bb = Bt + (size_t)(bn * 128) * K;

  for (int kt = 0; kt < K; kt += 32) {
    for (int p = 0; p < 2; ++p) {
      int slot = t + p * 256;
      int r = slot >> 2, c = (slot & 3) * 8;
      GLDS16(&Ab[(size_t)r * K + kt + c], &lA[slot * 8]);
      GLDS16(&Bb[(size_t)r * K + kt + c], &lB[slot * 8]);
    }
    __syncthreads();
    bf16x8 af[4], bfr[4];
    for (int i = 0; i < 4; ++i) af[i] = *(bf16x8*)&lA[(wm + i * 16 + ln) * 32 + qd * 8];
    for (int j = 0; j < 4; ++j) bfr[j] = *(bf16x8*)&lB[(wn + j * 16 + ln) * 32 + qd * 8];
    for (int i = 0; i < 4; ++i)
      for (int j = 0; j < 4; ++j)
        acc[i][j] = __builtin_amdgcn_mfma_f32_16x16x32_bf16(af[i], bfr[j], acc[i][j], 0, 0, 0);
    __syncthreads();
  }
  for (int i = 0; i < 4; ++i)
    for (int j = 0; j < 4; ++j) {
      int col = bn * 128 + wn + j * 16 + ln;
      float bv = bias[col];
      for (int r = 0; r < 4; ++r) {
        int row = bm * 128 + wm + i * 16 + qd * 4 + r;
        float v = acc[i][j][r] + bv;
        if (f32out) ((float*)C)[(size_t)row * N + col] = v;
        else ((bf16*)C)[(size_t)row * N + col] = __float2bfloat16(v);
      }
    }
}

// ---------------- flash attention (LD=32, causal); writes 512-wide attn ----------------
__global__ __launch_bounds__(256) void flash32(const bf16* __restrict__ qc,
                                               const bf16* __restrict__ kc,
                                               const bf16* __restrict__ vcT,
                                               bf16* __restrict__ attn) {
  __shared__ bf16 pbuf[4][16 * 40];
  int t = threadIdx.x;
  int lane = t & 63, w = t >> 6;
  int qd = lane >> 4, ln = lane & 15;
  int blk = blockIdx.x;
  int lt = blk & 31;
  int bh = blk >> 5, h = bh & 15, b = bh >> 4;
  int q0 = lt * 64 + w * 16;

  bf16x8 qf = *(const bf16x8*)&qc[((size_t)bh * Lseq + q0 + ln) * 32 + qd * 8];

  f32x4 o0 = {}, o1 = {};
  float m[4], lsum[4];
  for (int r = 0; r < 4; ++r) { m[r] = -1e30f; lsum[r] = 0.f; }
  const float scale = 0.17677669529663687f;  // 1/sqrt(32)

  int nkt = (q0 + 16 + 31) >> 5;
  bf16* pb = pbuf[w];
  for (int kt = 0; kt < nkt; ++kt) {
    int k0 = kt * 32;
    bf16x8 kf0 = *(const bf16x8*)&kc[((size_t)bh * Lseq + k0 + ln) * 32 + qd * 8];
    bf16x8 kf1 = *(const bf16x8*)&kc[((size_t)bh * Lseq + k0 + 16 + ln) * 32 + qd * 8];
    f32x4 s0 = {}, s1 = {};
    s0 = __builtin_amdgcn_mfma_f32_16x16x32_bf16(qf, kf0, s0, 0, 0, 0);
    s1 = __builtin_amdgcn_mfma_f32_16x16x32_bf16(qf, kf1, s1, 0, 0, 0);
    float sv0[4], sv1[4], alpha[4];
    for (int r = 0; r < 4; ++r) {
      int qrow = q0 + qd * 4 + r;
      sv0[r] = (k0 + ln <= qrow) ? s0[r] * scale : -1e30f;
      sv1[r] = (k0 + 16 + ln <= qrow) ? s1[r] * scale : -1e30f;
    }
    for (int r = 0; r < 4; ++r) {
      float mx = fmaxf(sv0[r], sv1[r]);
      for (int off = 1; off < 16; off <<= 1) mx = fmaxf(mx, __shfl_xor(mx, off, 64));
      float mn = fmaxf(m[r], mx);
      alpha[r] = __expf(m[r] - mn);
      m[r] = mn;
      sv0[r] = __expf(sv0[r] - mn);
      sv1[r] = __expf(sv1[r] - mn);
      float rs = sv0[r] + sv1[r];
      for (int off = 1; off < 16; off <<= 1) rs += __shfl_xor(rs, off, 64);
      lsum[r] = lsum[r] * alpha[r] + rs;
      o0[r] *= alpha[r];
      o1[r] *= alpha[r];
    }
    for (int r = 0; r < 4; ++r) {
      pb[(qd * 4 + r) * 40 + ln] = __float2bfloat16(sv0[r]);
      pb[(qd * 4 + r) * 40 + 16 + ln] = __float2bfloat16(sv1[r]);
    }
    asm volatile("s_waitcnt lgkmcnt(0)" ::: "memory");
    bf16x8 pf = *(bf16x8*)&pb[ln * 40 + qd * 8];
    bf16x8 vf0 = *(const bf16x8*)&vcT[((size_t)bh * 32 + ln) * Lseq + k0 + qd * 8];
    bf16x8 vf1 = *(const bf16x8*)&vcT[((size_t)bh * 32 + 16 + ln) * Lseq + k0 + qd * 8];
    o0 = __builtin_amdgcn_mfma_f32_16x16x32_bf16(pf, vf0, o0, 0, 0, 0);
    o1 = __builtin_amdgcn_mfma_f32_16x16x32_bf16(pf, vf1, o1, 0, 0, 0);
  }
  // epilogue: normalize, store 512-wide compressed attn (decompress folded into Wot)
  for (int r = 0; r < 4; ++r) {
    float inv = 1.0f / lsum[r];
    int l = q0 + qd * 4 + r;
    size_t base = ((size_t)(b * Lseq + l)) * 512 + h * 32;
    attn[base + ln] = __float2bfloat16(o0[r] * inv);
    attn[base + 16 + ln] = __float2bfloat16(o1[r] * inv);
  }
}

extern "C" void kernel_launch(void* const* d_in, const int* in_sizes, int n_in,
                              void* d_out, int out_size, void* d_ws, size_t ws_size,
                              hipStream_t stream) {
  const void* x = d_in[0];
  const void* cosS = d_in[1];
  const void* sinS = d_in[2];
  const void* Wq = d_in[3];
  const void* bq = d_in[4];
  const void* Wk = d_in[5];
  const void* bk = d_in[6];
  const void* Wv = d_in[7];
  const void* bv = d_in[8];
  const void* Wqc = d_in[9];
  const void* bqc = d_in[10];
  const void* Wkc = d_in[11];
  const void* bkc = d_in[12];
  const void* Wvc = d_in[13];
  const void* bvc = d_in[14];
  const void* Wd = d_in[15];
  const void* bd = d_in[16];
  const void* Wo = d_in[17];
  const void* bo = d_in[18];

  char* ws = (char*)d_ws;
  size_t off = 0;
  auto alloc = [&](size_t bytes) {
    char* p = ws + off;
    off += (bytes + 255) & ~(size_t)255;
    return p;
  };
  int* flag = (int*)alloc(256);
  bf16* small = (bf16*)alloc((size_t)SM_TOT * 2);
  bf16* wctG = (bf16*)alloc((size_t)12288 * 2);
  bf16* wdtG = (bf16*)alloc((size_t)4096 * 2);
  bf16* xb = (bf16*)alloc((size_t)4096 * 2048 * 2);
  bf16* WvB = (bf16*)alloc((size_t)2048 * 2048 * 2);
  bf16* WtQK = (bf16*)alloc((size_t)4096 * 2048 * 2);
  bf16* WtO = (bf16*)alloc((size_t)2048 * 2048 * 2);
  bf16* Wvt = (bf16*)alloc((size_t)512 * 2048 * 2);
  bf16* Wot = (bf16*)alloc((size_t)2048 * 512 * 2);
  float* boF = (float*)alloc((size_t)2048 * 4);
  float* bvF = (float*)alloc((size_t)512 * 4);
  bf16* qcW = (bf16*)alloc((size_t)65536 * 32 * 2);
  bf16* kcW = (bf16*)alloc((size_t)65536 * 32 * 2);
  bf16* vcTW = (bf16*)alloc((size_t)65536 * 32 * 2);
  bf16* attnW = (bf16*)alloc((size_t)4096 * 512 * 2);

  dim3 tb(256);
  detect_dtype<<<1, 64, 0, stream>>>((const ushort*)x, flag);
  prep<<<160, tb, 0, stream>>>(cosS, sinS, Wqc, Wkc, Wvc, bqc, bkc, bvc, Wd, bd, bo, bq,
                               bk, bv, small, wctG, wdtG, flag);
  transpose3<<<dim3(32, 32, 3), tb, 0, stream>>>(Wq, Wk, Wo, WtQK, WtO, flag);
  conv_x<<<4096, tb, 0, stream>>>(x, xb, flag);
  conv_x<<<2048, tb, 0, stream>>>(Wv, WvB, flag);
  fold_vw<<<dim3(16, 16), tb, 0, stream>>>(WvB, wctG, Wvt);
  fold_ow<<<dim3(16, 16), tb, 0, stream>>>(WtO, small, Wot);
  fold_bias<<<10, tb, 0, stream>>>(bo, bd, Wo, bv, bvc, Wvc, boF, bvF, flag);
  gemm_qkv_compress<<<dim3(36, 32), tb, 0, stream>>>(xb, WtQK, Wvt, small, wctG, bvF,
                                                     qcW, kcW, vcTW);
  flash32<<<1024, tb, 0, stream>>>(qcW, kcW, vcTW, attnW);
  gemm_bias_out<<<dim3(16, 32), tb, 0, stream>>>(attnW, Wot, boF, d_out, 4096, 2048,
                                                 512, flag);
}

// Round 2
// 490.154 us; speedup vs baseline: 1.5093x; 1.5093x over previous
//
#include <hip/hip_runtime.h>
#include <hip/hip_bf16.h>

// CausalMLA: B=2, L=2048, D=2048, H=16, HD=128, LD=32. Inputs fp32 or bf16
// (runtime-detected); pipeline bf16/MFMA; output dtype follows input.
// R4: RoPE+compress fused into QKV-GEMM epilogue.
// R5: algebraic folds — V compress folded into weights (W~v = Wv@Wvc),
//     decompress folded into output weights (W~o = Wd@Wo per head).
// R6: fold_bias was a 276us serial disaster (10 blocks, 2048-iter dependent
//     chains). Replaced with 2-stage parallel GEMV: 256-block coalesced
//     partial-reduce + tiny finalize. Everything else unchanged.

#define Bsz 2
#define Lseq 2048
#define Dmod 2048
#define Hn 16
#define HDim 128
#define LDim 32

typedef __bf16 bf16x8 __attribute__((ext_vector_type(8)));
typedef float f32x4 __attribute__((ext_vector_type(4)));
typedef __hip_bfloat16 bf16;

#define GLDS16(g, l)                                                    \
  __builtin_amdgcn_global_load_lds(                                     \
      (const __attribute__((address_space(1))) unsigned int*)(g),       \
      (__attribute__((address_space(3))) unsigned int*)(l), 16, 0, 0)

// ---- small-constants area layout (bf16 element offsets inside `small`) ----
#define SM_COS 0
#define SM_SIN 131072
#define SM_WC 262144     // Wqc|Wkc|Wvc 3*4096
#define SM_BC 274432     // bqc|bkc|bvc 3*32
#define SM_WD 274528     // 4096 (row-major Wd[e][hd] — used by fold_ow)
#define SM_BD 278624     // 128
#define SM_BO 278752     // 2048
#define SM_BQKV 280800   // bq|bk|bv 3*2048
#define SM_TOT 286944

// ---------------- dtype detector ----------------
__global__ void detect_dtype(const ushort* __restrict__ x, int* __restrict__ flag) {
  int t = threadIdx.x;  // 64 threads
  int bad = 0;
  for (int k = 0; k < 4; ++k) {
    ushort u = x[t * 4 + k];
    int ex = (u >> 7) & 0xFF;
    if (ex >= 0xC0) bad = 1;
  }
  unsigned long long b = __ballot(bad);
  if (t == 0) *flag = (b != 0ULL) ? 1 : 0;  // 1 = inputs are fp32
}

__device__ inline void conv8(const void* src, size_t so, bf16* dst, size_t dof, int f32) {
  if (f32) {
    const float* s = (const float*)src + so;
    bf16 tmp[8] __attribute__((aligned(16)));
    for (int j = 0; j < 8; ++j) tmp[j] = __float2bfloat16(s[j]);
    *(uint4*)&dst[dof] = *(uint4*)tmp;
  } else {
    *(uint4*)&dst[dof] = *(const uint4*)((const ushort*)src + so);
  }
}

__device__ inline float cv1(const void* s, size_t i, int f32) {
  return f32 ? ((const float*)s)[i] : __bfloat162float(((const bf16*)s)[i]);
}

__global__ __launch_bounds__(256) void conv_x(const void* __restrict__ xs,
                                              bf16* __restrict__ xd,
                                              const int* __restrict__ flagp) {
  int f32 = *flagp;
  size_t e = ((size_t)blockIdx.x * 256 + threadIdx.x) * 8;
  conv8(xs, e, xd, e, f32);
}

// ---------------- prep: small-area conversion + wctG/wdtG ----------------
__global__ __launch_bounds__(256) void prep(
    const void* cosS, const void* sinS, const void* WqcS, const void* WkcS,
    const void* WvcS, const void* bqcS, const void* bkcS, const void* bvcS,
    const void* WdS, const void* bdS, const void* boS, const void* bqS,
    const void* bkS, const void* bvS, bf16* __restrict__ dst,
    bf16* __restrict__ wctG, bf16* __restrict__ wdtG,
    const int* __restrict__ flagp) {
  int f32 = *flagp;
  int tid = blockIdx.x * 256 + threadIdx.x;  // grid 160 -> 40960
  if (tid < SM_TOT / 8) {
    size_t e = (size_t)tid * 8;
    const void* src;
    size_t so;
    if (e < SM_SIN) { src = cosS; so = e - SM_COS; }
    else if (e < SM_WC) { src = sinS; so = e - SM_SIN; }
    else if (e < SM_BC) { size_t r = e - SM_WC; src = (r < 4096) ? WqcS : (r < 8192) ? WkcS : WvcS; so = r & 4095; }
    else if (e < SM_WD) { size_t r = e - SM_BC; src = (r < 32) ? bqcS : (r < 64) ? bkcS : bvcS; so = r & 31; }
    else if (e < SM_BD) { src = WdS; so = e - SM_WD; }
    else if (e < SM_BO) { src = bdS; so = e - SM_BD; }
    else if (e < SM_BQKV) { src = boS; so = e - SM_BO; }
    else { size_t r = e - SM_BQKV; src = (r < 2048) ? bqS : (r < 4096) ? bkS : bvS; so = r & 2047; }
    conv8(src, so, dst, e, f32);
  } else {
    int idx = tid - SM_TOT / 8;
    for (int i = idx; i < 16384; i += 40960 - SM_TOT / 8) {
      if (i < 12288) {
        int reg = i >> 12, rem = i & 4095, n = rem >> 7, k = rem & 127;
        const void* src = (reg == 0) ? WqcS : (reg == 1) ? WkcS : WvcS;
        wctG[i] = __float2bfloat16(cv1(src, (size_t)k * 32 + n, f32));
      } else {
        int i2 = i - 12288, o = i2 >> 5, e = i2 & 31;
        wdtG[i2] = __float2bfloat16(cv1(WdS, (size_t)e * 128 + o, f32));
      }
    }
  }
}

// ---------------- 3 weight transposes: Wt[n][k] = W[k][n] (Wq, Wk, Wo) ----------------
__global__ __launch_bounds__(256) void transpose3(const void* __restrict__ WqS,
                                                  const void* __restrict__ WkS,
                                                  const void* __restrict__ WoS,
                                                  bf16* __restrict__ WtQK,
                                                  bf16* __restrict__ WtO,
                                                  const int* __restrict__ flagp) {
  __shared__ float tile[64][65];
  int f32 = *flagp;
  int z = blockIdx.z;
  const void* W = (z == 0) ? WqS : (z == 1) ? WkS : WoS;
  bf16* Wt = (z == 2) ? WtO : (WtQK + (size_t)z * 2048 * 2048);
  int n0 = blockIdx.x * 64, k0 = blockIdx.y * 64;
  int t = threadIdx.x;
  int x = (t & 7) * 8, y = t >> 3;
  for (int p = 0; p < 2; ++p) {
    int r = y + p * 32;
    if (f32) {
      const float* src = (const float*)W + (size_t)(k0 + r) * 2048 + n0 + x;
      float4 a = *(const float4*)src;
      float4 b2 = *(const float4*)(src + 4);
      tile[r][x + 0] = a.x; tile[r][x + 1] = a.y; tile[r][x + 2] = a.z; tile[r][x + 3] = a.w;
      tile[r][x + 4] = b2.x; tile[r][x + 5] = b2.y; tile[r][x + 6] = b2.z; tile[r][x + 7] = b2.w;
    } else {
      const ushort* src = (const ushort*)W + (size_t)(k0 + r) * 2048 + n0 + x;
      uint4 u = *(const uint4*)src;
      bf16* e = (bf16*)&u;
      for (int j = 0; j < 8; ++j) tile[r][x + j] = __bfloat162float(e[j]);
    }
  }
  __syncthreads();
  for (int p = 0; p < 2; ++p) {
    int n = y + p * 32;
    bf16 tmp[8] __attribute__((aligned(16)));
    for (int j = 0; j < 8; ++j) tmp[j] = __float2bfloat16(tile[x + j][n]);
    *(uint4*)&Wt[(size_t)(n0 + n) * 2048 + k0 + x] = *(uint4*)tmp;
  }
}

// ---------------- fold_vw: W~vt[(h*32+e)][d_in] = sum_hd Wvc^T[e][hd] * Wv[d_in][128h+hd] ----------------
__global__ __launch_bounds__(256) void fold_vw(const bf16* __restrict__ WvB,
                                               const bf16* __restrict__ wctG,
                                               bf16* __restrict__ Wvt) {
  int nb = blockIdx.x, h = blockIdx.y;
  int t = threadIdx.x, lane = t & 63, w = t >> 6;
  int qd = lane >> 4, ln = lane & 15;
  f32x4 acc[2][2] = {};
  for (int kt = 0; kt < 4; ++kt) {
    bf16x8 af[2], bfr[2];
    for (int i = 0; i < 2; ++i)
      af[i] = *(const bf16x8*)&wctG[8192 + (i * 16 + ln) * 128 + kt * 32 + qd * 8];
    for (int j = 0; j < 2; ++j)
      bfr[j] = *(const bf16x8*)&WvB[(size_t)(nb * 128 + w * 32 + j * 16 + ln) * 2048 +
                                    h * 128 + kt * 32 + qd * 8];
    for (int i = 0; i < 2; ++i)
      for (int j = 0; j < 2; ++j)
        acc[i][j] = __builtin_amdgcn_mfma_f32_16x16x32_bf16(af[i], bfr[j], acc[i][j], 0, 0, 0);
  }
  for (int i = 0; i < 2; ++i)
    for (int j = 0; j < 2; ++j)
      for (int r = 0; r < 4; ++r) {
        int e = i * 16 + qd * 4 + r;
        int col = nb * 128 + w * 32 + j * 16 + ln;
        Wvt[(size_t)(h * 32 + e) * 2048 + col] = __float2bfloat16(acc[i][j][r]);
      }
}

// ---------------- fold_ow: W~ot[d_out][(h*32+e)] = sum_hd Wd[e][hd] * WtO[d_out][128h+hd] ----------------
__global__ __launch_bounds__(256) void fold_ow(const bf16* __restrict__ WtO,
                                               const bf16* __restrict__ small,
                                               bf16* __restrict__ Wot) {
  int mb = blockIdx.x, h = blockIdx.y;
  int t = threadIdx.x, lane = t & 63, w = t >> 6;
  int qd = lane >> 4, ln = lane & 15;
  f32x4 acc[2][2] = {};
  for (int kt = 0; kt < 4; ++kt) {
    bf16x8 af[2], bfr[2];
    for (int i = 0; i < 2; ++i)
      af[i] = *(const bf16x8*)&WtO[(size_t)(mb * 128 + w * 32 + i * 16 + ln) * 2048 +
                                   h * 128 + kt * 32 + qd * 8];
    for (int j = 0; j < 2; ++j)
      bfr[j] = *(const bf16x8*)&small[SM_WD + (j * 16 + ln) * 128 + kt * 32 + qd * 8];
    for (int i = 0; i < 2; ++i)
      for (int j = 0; j < 2; ++j)
        acc[i][j] = __builtin_amdgcn_mfma_f32_16x16x32_bf16(af[i], bfr[j], acc[i][j], 0, 0, 0);
  }
  for (int i = 0; i < 2; ++i)
    for (int j = 0; j < 2; ++j)
      for (int r = 0; r < 4; ++r) {
        int row = mb * 128 + w * 32 + i * 16 + qd * 4 + r;
        int col = h * 32 + j * 16 + ln;
        Wot[(size_t)row * 512 + col] = __float2bfloat16(acc[i][j][r]);
      }
}

// ---------------- fold_bias stage 1: bo_part[kb][col] = sum_{k in kb*128..+128} bd[k&127]*Wo[k][col] ----------------
// grid (16 nb, 16 kb) x 256 threads; coalesced 128-float row segments.
__global__ __launch_bounds__(256) void fold_bias_partial(const void* WoS, const void* bdS,
                                                         float* __restrict__ bo_part,
                                                         const int* __restrict__ flagp) {
  __shared__ float red[256];
  int f32 = *flagp;
  int nb = blockIdx.x, kb = blockIdx.y;
  int t = threadIdx.x;
  int col = nb * 128 + (t & 127);
  int half = t >> 7;
  float s = 0.f;
  int kbase = kb * 128 + half * 64;
  for (int i = 0; i < 64; ++i) {
    int k = kbase + i;
    s += cv1(bdS, k & 127, f32) * cv1(WoS, (size_t)k * 2048 + col, f32);
  }
  red[t] = s;
  __syncthreads();
  if (half == 0) bo_part[kb * 2048 + col] = red[t] + red[t + 128];
}

// ---------------- fold_bias stage 2: boF = bo + sum_kb bo_part; bvF = bv@Wvc + bvc ----------------
__global__ __launch_bounds__(256) void fold_bias_final(const void* boS,
                                                       const float* __restrict__ bo_part,
                                                       const void* bvS, const void* bvcS,
                                                       const void* WvcS,
                                                       float* __restrict__ boF,
                                                       float* __restrict__ bvF,
                                                       const int* __restrict__ flagp) {
  int f32 = *flagp;
  int tid = blockIdx.x * 256 + threadIdx.x;  // grid 10 -> 2560
  if (tid < 2048) {
    float s = cv1(boS, tid, f32);
    for (int kb = 0; kb < 16; ++kb) s += bo_part[kb * 2048 + tid];
    boF[tid] = s;
  } else if (tid < 2560) {
    int j = tid - 2048, h = j >> 5, e = j & 31;
    float s = cv1(bvcS, e, f32);
    for (int hd = 0; hd < 128; ++hd)
      s += cv1(bvS, h * 128 + hd, f32) * cv1(WvcS, (size_t)hd * 32 + e, f32);
    bvF[j] = s;
  }
}

// ---------------- QKV GEMM: bn<32 = Q|K (fused RoPE+compress); bn>=32 = folded-V -> vcT ----------------
#define ESTR 136
__global__ __launch_bounds__(256) void gemm_qkv_compress(
    const bf16* __restrict__ A, const bf16* __restrict__ Bt,
    const bf16* __restrict__ Wvt, const bf16* __restrict__ small,
    const bf16* __restrict__ wctG, const float* __restrict__ bvF,
    bf16* __restrict__ qc, bf16* __restrict__ kc, bf16* __restrict__ vcT) {
  __shared__ bf16 sh[128 * ESTR];  // 34816 B; first 16KB doubles as lA|lB
  bf16* lA = sh;
  bf16* lB = sh + 4096;
  const int K = 2048;
  int bm = blockIdx.y, bn = blockIdx.x;
  int t = threadIdx.x;
  int lane = t & 63, w = t >> 6;
  int wm = (w >> 1) * 64, wn = (w & 1) * 64;
  int qd = lane >> 4, ln = lane & 15;

  f32x4 acc[4][4] = {};
  const bf16* Ab = A + (size_t)(bm * 128) * K;
  const bf16* Bb = (bn < 32) ? (Bt + (size_t)(bn * 128) * K)
                             : (Wvt + (size_t)((bn - 32) * 128) * K);

  for (int kt = 0; kt < K; kt += 32) {
    for (int p = 0; p < 2; ++p) {
      int slot = t + p * 256;
      int r = slot >> 2, c = (slot & 3) * 8;
      GLDS16(&Ab[(size_t)r * K + kt + c], &lA[slot * 8]);
      GLDS16(&Bb[(size_t)r * K + kt + c], &lB[slot * 8]);
    }
    __syncthreads();
    bf16x8 af[4], bfr[4];
    for (int i = 0; i < 4; ++i) af[i] = *(bf16x8*)&lA[(wm + i * 16 + ln) * 32 + qd * 8];
    for (int j = 0; j < 4; ++j) bfr[j] = *(bf16x8*)&lB[(wn + j * 16 + ln) * 32 + qd * 8];
    for (int i = 0; i < 4; ++i)
      for (int j = 0; j < 4; ++j)
        acc[i][j] = __builtin_amdgcn_mfma_f32_16x16x32_bf16(af[i], bfr[j], acc[i][j], 0, 0, 0);
    __syncthreads();
  }

  if (bn >= 32) {
    // folded-V epilogue: acc + bvF -> vcT[(b*512 + n)][l] (transposed write)
    int bn2 = bn - 32;
    int b = bm >> 4;
    for (int j = 0; j < 4; ++j) {
      int n = bn2 * 128 + wn + j * 16 + ln;
      float bb = bvF[n];
      for (int i = 0; i < 4; ++i) {
        int lbase = (bm & 15) * 128 + wm + i * 16 + qd * 4;
        bf16 p4[4] __attribute__((aligned(8)));
        for (int r = 0; r < 4; ++r) p4[r] = __float2bfloat16(acc[i][j][r] + bb);
        *(uint2*)&vcT[((size_t)(b * 512 + n)) * 2048 + lbase] = *(uint2*)p4;
      }
    }
    return;
  }

  int reg = bn >> 4, h = bn & 15;
  // epilogue 1: acc + bias -> LDS tile (row = block-local l, col = head dim)
  for (int j = 0; j < 4; ++j) {
    int col = wn + j * 16 + ln;
    float bv = __bfloat162float(small[SM_BQKV + bn * 128 + col]);
    for (int i = 0; i < 4; ++i)
      for (int r = 0; r < 4; ++r)
        sh[(wm + i * 16 + qd * 4 + r) * ESTR + col] = __float2bfloat16(acc[i][j][r] + bv);
  }
  __syncthreads();

  // epilogue 2: RoPE + compress 32 l-rows per wave
  int r0 = w * 32;
  int b = bm >> 4;
  int bh = b * Hn + h;
  bf16x8 bfr2[2][4];
  for (int nt = 0; nt < 2; ++nt)
    for (int kt = 0; kt < 4; ++kt)
      bfr2[nt][kt] = *(const bf16x8*)&wctG[reg * 4096 + (nt * 16 + ln) * 128 + kt * 32 + qd * 8];
  float bc[2];
  bc[0] = __bfloat162float(small[SM_BC + reg * 32 + ln]);
  bc[1] = __bfloat162float(small[SM_BC + reg * 32 + 16 + ln]);

  for (int mt = 0; mt < 2; ++mt) {
    int lb = r0 + mt * 16 + ln;
    int lg = (bm & 15) * 128 + lb;
    f32x4 c2[2] = {};
    for (int kt = 0; kt < 4; ++kt) {
      uint4 u = *(uint4*)&sh[lb * ESTR + kt * 32 + qd * 8];
      bf16* e8 = (bf16*)&u;
      int pbase = kt * 16 + qd * 4;
      for (int j = 0; j < 4; ++j) {
        float cvv = __bfloat162float(small[SM_COS + (size_t)lg * 64 + pbase + j]);
        float svv = __bfloat162float(small[SM_SIN + (size_t)lg * 64 + pbase + j]);
        float ev = __bfloat162float(e8[2 * j]);
        float ov = __bfloat162float(e8[2 * j + 1]);
        e8[2 * j] = __float2bfloat16(ev * cvv - ov * svv);
        e8[2 * j + 1] = __float2bfloat16(ev * svv + ov * cvv);
      }
      bf16x8 a = *(bf16x8*)&u;
      c2[0] = __builtin_amdgcn_mfma_f32_16x16x32_bf16(a, bfr2[0][kt], c2[0], 0, 0, 0);
      c2[1] = __builtin_amdgcn_mfma_f32_16x16x32_bf16(a, bfr2[1][kt], c2[1], 0, 0, 0);
    }
    int lgbase = (bm & 15) * 128 + r0 + mt * 16 + qd * 4;
    bf16* dst = (reg == 0) ? qc : kc;
    for (int nt = 0; nt < 2; ++nt)
      for (int r = 0; r < 4; ++r)
        dst[((size_t)bh * Lseq + lgbase + r) * 32 + nt * 16 + ln] =
            __float2bfloat16(c2[nt][r] + bc[nt]);
  }
}

// ---------------- output GEMM: d_out = attn @ Wot^T + boF (fp32 bias), K=512 ----------------
__global__ __launch_bounds__(256) void gemm_bias_out(const bf16* __restrict__ A,
                                                     const bf16* __restrict__ Bt,
                                                     const float* __restrict__ bias,
                                                     void* __restrict__ C,
                                                     int M, int N, int K,
                                                     const int* __restrict__ flagp) {
  __shared__ bf16 lA[128 * 32];
  __shared__ bf16 lB[128 * 32];
  int f32out = *flagp;
  int bm = blockIdx.y, bn = blockIdx.x;
  int t = threadIdx.x;
  int lane = t & 63, w = t >> 6;
  int wm = (w >> 1) * 64, wn = (w & 1) * 64;
  int qd = lane >> 4, ln = lane & 15;

  f32x4 acc[4][4] = {};
  const bf16* Ab = A + (size_t)(bm * 128) * K;
  const bf16* Bb = Bt + (size_t)(bn * 128) * K;

  for (int kt = 0; kt < K; kt += 32) {
    for (int p = 0; p < 2; ++p) {
      int slot = t + p * 256;
      int r = slot >> 2, c = (slot & 3) * 8;
      GLDS16(&Ab[(size_t)r * K + kt + c], &lA[slot * 8]);
      GLDS16(&Bb[(size_t)r * K + kt + c], &lB[slot * 8]);
    }
    __syncthreads();
    bf16x8 af[4], bfr[4];
    for (int i = 0; i < 4; ++i) af[i] = *(bf16x8*)&lA[(wm + i * 16 + ln) * 32 + qd * 8];
    for (int j = 0; j < 4; ++j) bfr[j] = *(bf16x8*)&lB[(wn + j * 16 + ln) * 32 + qd * 8];
    for (int i = 0; i < 4; ++i)
      for (int j = 0; j < 4; ++j)
        acc[i][j] = __builtin_amdgcn_mfma_f32_16x16x32_bf16(af[i], bfr[j], acc[i][j], 0, 0, 0);
    __syncthreads();
  }
  for (int i = 0; i < 4; ++i)
    for (int j = 0; j < 4; ++j) {
      int col = bn * 128 + wn + j * 16 + ln;
      float bv = bias[col];
      for (int r = 0; r < 4; ++r) {
        int row = bm * 128 + wm + i * 16 + qd * 4 + r;
        float v = acc[i][j][r] + bv;
        if (f32out) ((float*)C)[(size_t)row * N + col] = v;
        else ((bf16*)C)[(size_t)row * N + col] = __float2bfloat16(v);
      }
    }
}

// ---------------- flash attention (LD=32, causal); writes 512-wide attn ----------------
__global__ __launch_bounds__(256) void flash32(const bf16* __restrict__ qc,
                                               const bf16* __restrict__ kc,
                                               const bf16* __restrict__ vcT,
                                               bf16* __restrict__ attn) {
  __shared__ bf16 pbuf[4][16 * 40];
  int t = threadIdx.x;
  int lane = t & 63, w = t >> 6;
  int qd = lane >> 4, ln = lane & 15;
  int blk = blockIdx.x;
  int lt = blk & 31;
  int bh = blk >> 5, h = bh & 15, b = bh >> 4;
  int q0 = lt * 64 + w * 16;

  bf16x8 qf = *(const bf16x8*)&qc[((size_t)bh * Lseq + q0 + ln) * 32 + qd * 8];

  f32x4 o0 = {}, o1 = {};
  float m[4], lsum[4];
  for (int r = 0; r < 4; ++r) { m[r] = -1e30f; lsum[r] = 0.f; }
  const float scale = 0.17677669529663687f;  // 1/sqrt(32)

  int nkt = (q0 + 16 + 31) >> 5;
  bf16* pb = pbuf[w];
  for (int kt = 0; kt < nkt; ++kt) {
    int k0 = kt * 32;
    bf16x8 kf0 = *(const bf16x8*)&kc[((size_t)bh * Lseq + k0 + ln) * 32 + qd * 8];
    bf16x8 kf1 = *(const bf16x8*)&kc[((size_t)bh * Lseq + k0 + 16 + ln) * 32 + qd * 8];
    f32x4 s0 = {}, s1 = {};
    s0 = __builtin_amdgcn_mfma_f32_16x16x32_bf16(qf, kf0, s0, 0, 0, 0);
    s1 = __builtin_amdgcn_mfma_f32_16x16x32_bf16(qf, kf1, s1, 0, 0, 0);
    float sv0[4], sv1[4], alpha[4];
    for (int r = 0; r < 4; ++r) {
      int qrow = q0 + qd * 4 + r;
      sv0[r] = (k0 + ln <= qrow) ? s0[r] * scale : -1e30f;
      sv1[r] = (k0 + 16 + ln <= qrow) ? s1[r] * scale : -1e30f;
    }
    for (int r = 0; r < 4; ++r) {
      float mx = fmaxf(sv0[r], sv1[r]);
      for (int off = 1; off < 16; off <<= 1) mx = fmaxf(mx, __shfl_xor(mx, off, 64));
      float mn = fmaxf(m[r], mx);
      alpha[r] = __expf(m[r] - mn);
      m[r] = mn;
      sv0[r] = __expf(sv0[r] - mn);
      sv1[r] = __expf(sv1[r] - mn);
      float rs = sv0[r] + sv1[r];
      for (int off = 1; off < 16; off <<= 1) rs += __shfl_xor(rs, off, 64);
      lsum[r] = lsum[r] * alpha[r] + rs;
      o0[r] *= alpha[r];
      o1[r] *= alpha[r];
    }
    for (int r = 0; r < 4; ++r) {
      pb[(qd * 4 + r) * 40 + ln] = __float2bfloat16(sv0[r]);
      pb[(qd * 4 + r) * 40 + 16 + ln] = __float2bfloat16(sv1[r]);
    }
    asm volatile("s_waitcnt lgkmcnt(0)" ::: "memory");
    bf16x8 pf = *(bf16x8*)&pb[ln * 40 + qd * 8];
    bf16x8 vf0 = *(const bf16x8*)&vcT[((size_t)bh * 32 + ln) * Lseq + k0 + qd * 8];
    bf16x8 vf1 = *(const bf16x8*)&vcT[((size_t)bh * 32 + 16 + ln) * Lseq + k0 + qd * 8];
    o0 = __builtin_amdgcn_mfma_f32_16x16x32_bf16(pf, vf0, o0, 0, 0, 0);
    o1 = __builtin_amdgcn_mfma_f32_16x16x32_bf16(pf, vf1, o1, 0, 0, 0);
  }
  // epilogue: normalize, store 512-wide compressed attn (decompress folded into Wot)
  for (int r = 0; r < 4; ++r) {
    float inv = 1.0f / lsum[r];
    int l = q0 + qd * 4 + r;
    size_t base = ((size_t)(b * Lseq + l)) * 512 + h * 32;
    attn[base + ln] = __float2bfloat16(o0[r] * inv);
    attn[base + 16 + ln] = __float2bfloat16(o1[r] * inv);
  }
}

extern "C" void kernel_launch(void* const* d_in, const int* in_sizes, int n_in,
                              void* d_out, int out_size, void* d_ws, size_t ws_size,
                              hipStream_t stream) {
  const void* x = d_in[0];
  const void* cosS = d_in[1];
  const void* sinS = d_in[2];
  const void* Wq = d_in[3];
  const void* bq = d_in[4];
  const void* Wk = d_in[5];
  const void* bk = d_in[6];
  const void* Wv = d_in[7];
  const void* bv = d_in[8];
  const void* Wqc = d_in[9];
  const void* bqc = d_in[10];
  const void* Wkc = d_in[11];
  const void* bkc = d_in[12];
  const void* Wvc = d_in[13];
  const void* bvc = d_in[14];
  const void* Wd = d_in[15];
  const void* bd = d_in[16];
  const void* Wo = d_in[17];
  const void* bo = d_in[18];

  char* ws = (char*)d_ws;
  size_t off = 0;
  auto alloc = [&](size_t bytes) {
    char* p = ws + off;
    off += (bytes + 255) & ~(size_t)255;
    return p;
  };
  int* flag = (int*)alloc(256);
  bf16* small = (bf16*)alloc((size_t)SM_TOT * 2);
  bf16* wctG = (bf16*)alloc((size_t)12288 * 2);
  bf16* wdtG = (bf16*)alloc((size_t)4096 * 2);
  bf16* xb = (bf16*)alloc((size_t)4096 * 2048 * 2);
  bf16* WvB = (bf16*)alloc((size_t)2048 * 2048 * 2);
  bf16* WtQK = (bf16*)alloc((size_t)4096 * 2048 * 2);
  bf16* WtO = (bf16*)alloc((size_t)2048 * 2048 * 2);
  bf16* Wvt = (bf16*)alloc((size_t)512 * 2048 * 2);
  bf16* Wot = (bf16*)alloc((size_t)2048 * 512 * 2);
  float* bo_part = (float*)alloc((size_t)16 * 2048 * 4);
  float* boF = (float*)alloc((size_t)2048 * 4);
  float* bvF = (float*)alloc((size_t)512 * 4);
  bf16* qcW = (bf16*)alloc((size_t)65536 * 32 * 2);
  bf16* kcW = (bf16*)alloc((size_t)65536 * 32 * 2);
  bf16* vcTW = (bf16*)alloc((size_t)65536 * 32 * 2);
  bf16* attnW = (bf16*)alloc((size_t)4096 * 512 * 2);

  dim3 tb(256);
  detect_dtype<<<1, 64, 0, stream>>>((const ushort*)x, flag);
  prep<<<160, tb, 0, stream>>>(cosS, sinS, Wqc, Wkc, Wvc, bqc, bkc, bvc, Wd, bd, bo, bq,
                               bk, bv, small, wctG, wdtG, flag);
  transpose3<<<dim3(32, 32, 3), tb, 0, stream>>>(Wq, Wk, Wo, WtQK, WtO, flag);
  conv_x<<<4096, tb, 0, stream>>>(x, xb, flag);
  conv_x<<<2048, tb, 0, stream>>>(Wv, WvB, flag);
  fold_vw<<<dim3(16, 16), tb, 0, stream>>>(WvB, wctG, Wvt);
  fold_ow<<<dim3(16, 16), tb, 0, stream>>>(WtO, small, Wot);
  fold_bias_partial<<<dim3(16, 16), tb, 0, stream>>>(Wo, bd, bo_part, flag);
  fold_bias_final<<<10, tb, 0, stream>>>(bo, bo_part, bv, bvc, Wvc, boF, bvF, flag);
  gemm_qkv_compress<<<dim3(36, 32), tb, 0, stream>>>(xb, WtQK, Wvt, small, wctG, bvF,
                                                     qcW, kcW, vcTW);
  flash32<<<1024, tb, 0, stream>>>(qcW, kcW, vcTW, attnW);
  gemm_bias_out<<<dim3(16, 32), tb, 0, stream>>>(attnW, Wot, boF, d_out, 4096, 2048,
                                                 512, flag);
}

// Round 3
// 477.834 us; speedup vs baseline: 1.5482x; 1.0258x over previous
//
#include <hip/hip_runtime.h>
#include <hip/hip_bf16.h>

// CausalMLA: B=2, L=2048, D=2048, H=16, HD=128, LD=32. Inputs fp32 or bf16
// (runtime-detected); pipeline bf16/MFMA; output dtype follows input.
// R4: RoPE+compress fused into QKV-GEMM epilogue.
// R5: algebraic folds — V compress folded into weights (W~v = Wv@Wvc),
//     decompress folded into output weights (W~o = Wd@Wo per head).
// R6: fold_bias parallelized (was 276us serial).
// R7: merged QK+V GEMM had dual-epilogue VGPR bloat (72->108, occupancy
//     31->18%, 140->160us). Split into lean gemm_qk_compress (R0-proven
//     path, grid 32x32) + dedicated gemm_v_fold (64x64 tile, 512 blocks).

#define Bsz 2
#define Lseq 2048
#define Dmod 2048
#define Hn 16
#define HDim 128
#define LDim 32

typedef __bf16 bf16x8 __attribute__((ext_vector_type(8)));
typedef float f32x4 __attribute__((ext_vector_type(4)));
typedef __hip_bfloat16 bf16;

#define GLDS16(g, l)                                                    \
  __builtin_amdgcn_global_load_lds(                                     \
      (const __attribute__((address_space(1))) unsigned int*)(g),       \
      (__attribute__((address_space(3))) unsigned int*)(l), 16, 0, 0)

// ---- small-constants area layout (bf16 element offsets inside `small`) ----
#define SM_COS 0
#define SM_SIN 131072
#define SM_WC 262144     // Wqc|Wkc|Wvc 3*4096
#define SM_BC 274432     // bqc|bkc|bvc 3*32
#define SM_WD 274528     // 4096 (row-major Wd[e][hd] — used by fold_ow)
#define SM_BD 278624     // 128
#define SM_BO 278752     // 2048
#define SM_BQKV 280800   // bq|bk|bv 3*2048
#define SM_TOT 286944

// ---------------- dtype detector ----------------
__global__ void detect_dtype(const ushort* __restrict__ x, int* __restrict__ flag) {
  int t = threadIdx.x;  // 64 threads
  int bad = 0;
  for (int k = 0; k < 4; ++k) {
    ushort u = x[t * 4 + k];
    int ex = (u >> 7) & 0xFF;
    if (ex >= 0xC0) bad = 1;
  }
  unsigned long long b = __ballot(bad);
  if (t == 0) *flag = (b != 0ULL) ? 1 : 0;  // 1 = inputs are fp32
}

__device__ inline void conv8(const void* src, size_t so, bf16* dst, size_t dof, int f32) {
  if (f32) {
    const float* s = (const float*)src + so;
    bf16 tmp[8] __attribute__((aligned(16)));
    for (int j = 0; j < 8; ++j) tmp[j] = __float2bfloat16(s[j]);
    *(uint4*)&dst[dof] = *(uint4*)tmp;
  } else {
    *(uint4*)&dst[dof] = *(const uint4*)((const ushort*)src + so);
  }
}

__device__ inline float cv1(const void* s, size_t i, int f32) {
  return f32 ? ((const float*)s)[i] : __bfloat162float(((const bf16*)s)[i]);
}

__global__ __launch_bounds__(256) void conv_x(const void* __restrict__ xs,
                                              bf16* __restrict__ xd,
                                              const int* __restrict__ flagp) {
  int f32 = *flagp;
  size_t e = ((size_t)blockIdx.x * 256 + threadIdx.x) * 8;
  conv8(xs, e, xd, e, f32);
}

// ---------------- prep: small-area conversion + wctG/wdtG ----------------
__global__ __launch_bounds__(256) void prep(
    const void* cosS, const void* sinS, const void* WqcS, const void* WkcS,
    const void* WvcS, const void* bqcS, const void* bkcS, const void* bvcS,
    const void* WdS, const void* bdS, const void* boS, const void* bqS,
    const void* bkS, const void* bvS, bf16* __restrict__ dst,
    bf16* __restrict__ wctG, bf16* __restrict__ wdtG,
    const int* __restrict__ flagp) {
  int f32 = *flagp;
  int tid = blockIdx.x * 256 + threadIdx.x;  // grid 160 -> 40960
  if (tid < SM_TOT / 8) {
    size_t e = (size_t)tid * 8;
    const void* src;
    size_t so;
    if (e < SM_SIN) { src = cosS; so = e - SM_COS; }
    else if (e < SM_WC) { src = sinS; so = e - SM_SIN; }
    else if (e < SM_BC) { size_t r = e - SM_WC; src = (r < 4096) ? WqcS : (r < 8192) ? WkcS : WvcS; so = r & 4095; }
    else if (e < SM_WD) { size_t r = e - SM_BC; src = (r < 32) ? bqcS : (r < 64) ? bkcS : bvcS; so = r & 31; }
    else if (e < SM_BD) { src = WdS; so = e - SM_WD; }
    else if (e < SM_BO) { src = bdS; so = e - SM_BD; }
    else if (e < SM_BQKV) { src = boS; so = e - SM_BO; }
    else { size_t r = e - SM_BQKV; src = (r < 2048) ? bqS : (r < 4096) ? bkS : bvS; so = r & 2047; }
    conv8(src, so, dst, e, f32);
  } else {
    int idx = tid - SM_TOT / 8;
    for (int i = idx; i < 16384; i += 40960 - SM_TOT / 8) {
      if (i < 12288) {
        int reg = i >> 12, rem = i & 4095, n = rem >> 7, k = rem & 127;
        const void* src = (reg == 0) ? WqcS : (reg == 1) ? WkcS : WvcS;
        wctG[i] = __float2bfloat16(cv1(src, (size_t)k * 32 + n, f32));
      } else {
        int i2 = i - 12288, o = i2 >> 5, e = i2 & 31;
        wdtG[i2] = __float2bfloat16(cv1(WdS, (size_t)e * 128 + o, f32));
      }
    }
  }
}

// ---------------- 3 weight transposes: Wt[n][k] = W[k][n] (Wq, Wk, Wo) ----------------
__global__ __launch_bounds__(256) void transpose3(const void* __restrict__ WqS,
                                                  const void* __restrict__ WkS,
                                                  const void* __restrict__ WoS,
                                                  bf16* __restrict__ WtQK,
                                                  bf16* __restrict__ WtO,
                                                  const int* __restrict__ flagp) {
  __shared__ float tile[64][65];
  int f32 = *flagp;
  int z = blockIdx.z;
  const void* W = (z == 0) ? WqS : (z == 1) ? WkS : WoS;
  bf16* Wt = (z == 2) ? WtO : (WtQK + (size_t)z * 2048 * 2048);
  int n0 = blockIdx.x * 64, k0 = blockIdx.y * 64;
  int t = threadIdx.x;
  int x = (t & 7) * 8, y = t >> 3;
  for (int p = 0; p < 2; ++p) {
    int r = y + p * 32;
    if (f32) {
      const float* src = (const float*)W + (size_t)(k0 + r) * 2048 + n0 + x;
      float4 a = *(const float4*)src;
      float4 b2 = *(const float4*)(src + 4);
      tile[r][x + 0] = a.x; tile[r][x + 1] = a.y; tile[r][x + 2] = a.z; tile[r][x + 3] = a.w;
      tile[r][x + 4] = b2.x; tile[r][x + 5] = b2.y; tile[r][x + 6] = b2.z; tile[r][x + 7] = b2.w;
    } else {
      const ushort* src = (const ushort*)W + (size_t)(k0 + r) * 2048 + n0 + x;
      uint4 u = *(const uint4*)src;
      bf16* e = (bf16*)&u;
      for (int j = 0; j < 8; ++j) tile[r][x + j] = __bfloat162float(e[j]);
    }
  }
  __syncthreads();
  for (int p = 0; p < 2; ++p) {
    int n = y + p * 32;
    bf16 tmp[8] __attribute__((aligned(16)));
    for (int j = 0; j < 8; ++j) tmp[j] = __float2bfloat16(tile[x + j][n]);
    *(uint4*)&Wt[(size_t)(n0 + n) * 2048 + k0 + x] = *(uint4*)tmp;
  }
}

// ---------------- fold_vw: W~vt[(h*32+e)][d_in] = sum_hd Wvc^T[e][hd] * Wv[d_in][128h+hd] ----------------
__global__ __launch_bounds__(256) void fold_vw(const bf16* __restrict__ WvB,
                                               const bf16* __restrict__ wctG,
                                               bf16* __restrict__ Wvt) {
  int nb = blockIdx.x, h = blockIdx.y;
  int t = threadIdx.x, lane = t & 63, w = t >> 6;
  int qd = lane >> 4, ln = lane & 15;
  f32x4 acc[2][2] = {};
  for (int kt = 0; kt < 4; ++kt) {
    bf16x8 af[2], bfr[2];
    for (int i = 0; i < 2; ++i)
      af[i] = *(const bf16x8*)&wctG[8192 + (i * 16 + ln) * 128 + kt * 32 + qd * 8];
    for (int j = 0; j < 2; ++j)
      bfr[j] = *(const bf16x8*)&WvB[(size_t)(nb * 128 + w * 32 + j * 16 + ln) * 2048 +
                                    h * 128 + kt * 32 + qd * 8];
    for (int i = 0; i < 2; ++i)
      for (int j = 0; j < 2; ++j)
        acc[i][j] = __builtin_amdgcn_mfma_f32_16x16x32_bf16(af[i], bfr[j], acc[i][j], 0, 0, 0);
  }
  for (int i = 0; i < 2; ++i)
    for (int j = 0; j < 2; ++j)
      for (int r = 0; r < 4; ++r) {
        int e = i * 16 + qd * 4 + r;
        int col = nb * 128 + w * 32 + j * 16 + ln;
        Wvt[(size_t)(h * 32 + e) * 2048 + col] = __float2bfloat16(acc[i][j][r]);
      }
}

// ---------------- fold_ow: W~ot[d_out][(h*32+e)] = sum_hd Wd[e][hd] * WtO[d_out][128h+hd] ----------------
__global__ __launch_bounds__(256) void fold_ow(const bf16* __restrict__ WtO,
                                               const bf16* __restrict__ small,
                                               bf16* __restrict__ Wot) {
  int mb = blockIdx.x, h = blockIdx.y;
  int t = threadIdx.x, lane = t & 63, w = t >> 6;
  int qd = lane >> 4, ln = lane & 15;
  f32x4 acc[2][2] = {};
  for (int kt = 0; kt < 4; ++kt) {
    bf16x8 af[2], bfr[2];
    for (int i = 0; i < 2; ++i)
      af[i] = *(const bf16x8*)&WtO[(size_t)(mb * 128 + w * 32 + i * 16 + ln) * 2048 +
                                   h * 128 + kt * 32 + qd * 8];
    for (int j = 0; j < 2; ++j)
      bfr[j] = *(const bf16x8*)&small[SM_WD + (j * 16 + ln) * 128 + kt * 32 + qd * 8];
    for (int i = 0; i < 2; ++i)
      for (int j = 0; j < 2; ++j)
        acc[i][j] = __builtin_amdgcn_mfma_f32_16x16x32_bf16(af[i], bfr[j], acc[i][j], 0, 0, 0);
  }
  for (int i = 0; i < 2; ++i)
    for (int j = 0; j < 2; ++j)
      for (int r = 0; r < 4; ++r) {
        int row = mb * 128 + w * 32 + i * 16 + qd * 4 + r;
        int col = h * 32 + j * 16 + ln;
        Wot[(size_t)row * 512 + col] = __float2bfloat16(acc[i][j][r]);
      }
}

// ---------------- fold_bias stage 1 ----------------
__global__ __launch_bounds__(256) void fold_bias_partial(const void* WoS, const void* bdS,
                                                         float* __restrict__ bo_part,
                                                         const int* __restrict__ flagp) {
  __shared__ float red[256];
  int f32 = *flagp;
  int nb = blockIdx.x, kb = blockIdx.y;
  int t = threadIdx.x;
  int col = nb * 128 + (t & 127);
  int half = t >> 7;
  float s = 0.f;
  int kbase = kb * 128 + half * 64;
  for (int i = 0; i < 64; ++i) {
    int k = kbase + i;
    s += cv1(bdS, k & 127, f32) * cv1(WoS, (size_t)k * 2048 + col, f32);
  }
  red[t] = s;
  __syncthreads();
  if (half == 0) bo_part[kb * 2048 + col] = red[t] + red[t + 128];
}

// ---------------- fold_bias stage 2 ----------------
__global__ __launch_bounds__(256) void fold_bias_final(const void* boS,
                                                       const float* __restrict__ bo_part,
                                                       const void* bvS, const void* bvcS,
                                                       const void* WvcS,
                                                       float* __restrict__ boF,
                                                       float* __restrict__ bvF,
                                                       const int* __restrict__ flagp) {
  int f32 = *flagp;
  int tid = blockIdx.x * 256 + threadIdx.x;  // grid 10 -> 2560
  if (tid < 2048) {
    float s = cv1(boS, tid, f32);
    for (int kb = 0; kb < 16; ++kb) s += bo_part[kb * 2048 + tid];
    boF[tid] = s;
  } else if (tid < 2560) {
    int j = tid - 2048, h = j >> 5, e = j & 31;
    float s = cv1(bvcS, e, f32);
    for (int hd = 0; hd < 128; ++hd)
      s += cv1(bvS, h * 128 + hd, f32) * cv1(WvcS, (size_t)hd * 32 + e, f32);
    bvF[j] = s;
  }
}

// ---------------- QK GEMM + fused RoPE + compression (bn 0..31) ----------------
#define ESTR 136
__global__ __launch_bounds__(256) void gemm_qk_compress(
    const bf16* __restrict__ A, const bf16* __restrict__ Bt,
    const bf16* __restrict__ small, const bf16* __restrict__ wctG,
    bf16* __restrict__ qc, bf16* __restrict__ kc) {
  __shared__ bf16 sh[128 * ESTR];  // 34816 B; first 16KB doubles as lA|lB
  bf16* lA = sh;
  bf16* lB = sh + 4096;
  const int K = 2048;
  int bm = blockIdx.y, bn = blockIdx.x;
  int reg = bn >> 4, h = bn & 15;
  int t = threadIdx.x;
  int lane = t & 63, w = t >> 6;
  int wm = (w >> 1) * 64, wn = (w & 1) * 64;
  int qd = lane >> 4, ln = lane & 15;

  f32x4 acc[4][4] = {};
  const bf16* Ab = A + (size_t)(bm * 128) * K;
  const bf16* Bb = Bt + (size_t)(bn * 128) * K;

  for (int kt = 0; kt < K; kt += 32) {
    for (int p = 0; p < 2; ++p) {
      int slot = t + p * 256;
      int r = slot >> 2, c = (slot & 3) * 8;
      GLDS16(&Ab[(size_t)r * K + kt + c], &lA[slot * 8]);
      GLDS16(&Bb[(size_t)r * K + kt + c], &lB[slot * 8]);
    }
    __syncthreads();
    bf16x8 af[4], bfr[4];
    for (int i = 0; i < 4; ++i) af[i] = *(bf16x8*)&lA[(wm + i * 16 + ln) * 32 + qd * 8];
    for (int j = 0; j < 4; ++j) bfr[j] = *(bf16x8*)&lB[(wn + j * 16 + ln) * 32 + qd * 8];
    for (int i = 0; i < 4; ++i)
      for (int j = 0; j < 4; ++j)
        acc[i][j] = __builtin_amdgcn_mfma_f32_16x16x32_bf16(af[i], bfr[j], acc[i][j], 0, 0, 0);
    __syncthreads();
  }

  // epilogue 1: acc + bias -> LDS tile (row = block-local l, col = head dim)
  for (int j = 0; j < 4; ++j) {
    int col = wn + j * 16 + ln;
    float bv = __bfloat162float(small[SM_BQKV + bn * 128 + col]);
    for (int i = 0; i < 4; ++i)
      for (int r = 0; r < 4; ++r)
        sh[(wm + i * 16 + qd * 4 + r) * ESTR + col] = __float2bfloat16(acc[i][j][r] + bv);
  }
  __syncthreads();

  // epilogue 2: RoPE + compress 32 l-rows per wave
  int r0 = w * 32;
  int b = bm >> 4;
  int bh = b * Hn + h;
  bf16x8 bfr2[2][4];
  for (int nt = 0; nt < 2; ++nt)
    for (int kt = 0; kt < 4; ++kt)
      bfr2[nt][kt] = *(const bf16x8*)&wctG[reg * 4096 + (nt * 16 + ln) * 128 + kt * 32 + qd * 8];
  float bc[2];
  bc[0] = __bfloat162float(small[SM_BC + reg * 32 + ln]);
  bc[1] = __bfloat162float(small[SM_BC + reg * 32 + 16 + ln]);

  for (int mt = 0; mt < 2; ++mt) {
    int lb = r0 + mt * 16 + ln;
    int lg = (bm & 15) * 128 + lb;
    f32x4 c2[2] = {};
    for (int kt = 0; kt < 4; ++kt) {
      uint4 u = *(uint4*)&sh[lb * ESTR + kt * 32 + qd * 8];
      bf16* e8 = (bf16*)&u;
      int pbase = kt * 16 + qd * 4;
      for (int j = 0; j < 4; ++j) {
        float cvv = __bfloat162float(small[SM_COS + (size_t)lg * 64 + pbase + j]);
        float svv = __bfloat162float(small[SM_SIN + (size_t)lg * 64 + pbase + j]);
        float ev = __bfloat162float(e8[2 * j]);
        float ov = __bfloat162float(e8[2 * j + 1]);
        e8[2 * j] = __float2bfloat16(ev * cvv - ov * svv);
        e8[2 * j + 1] = __float2bfloat16(ev * svv + ov * cvv);
      }
      bf16x8 a = *(bf16x8*)&u;
      c2[0] = __builtin_amdgcn_mfma_f32_16x16x32_bf16(a, bfr2[0][kt], c2[0], 0, 0, 0);
      c2[1] = __builtin_amdgcn_mfma_f32_16x16x32_bf16(a, bfr2[1][kt], c2[1], 0, 0, 0);
    }
    int lgbase = (bm & 15) * 128 + r0 + mt * 16 + qd * 4;
    bf16* dst = (reg == 0) ? qc : kc;
    for (int nt = 0; nt < 2; ++nt)
      for (int r = 0; r < 4; ++r)
        dst[((size_t)bh * Lseq + lgbase + r) * 32 + nt * 16 + ln] =
            __float2bfloat16(c2[nt][r] + bc[nt]);
  }
}

// ---------------- V-fold GEMM: vcT[(b*512+n)][l] = x @ W~vt^T + bvF ----------------
// 64x64 tile, grid (8 nb, 64 mb) = 512 blocks (2 blocks/CU), 8KB LDS.
__global__ __launch_bounds__(256) void gemm_v_fold(const bf16* __restrict__ A,
                                                   const bf16* __restrict__ Wvt,
                                                   const float* __restrict__ bvF,
                                                   bf16* __restrict__ vcT) {
  __shared__ bf16 lA[64 * 32];
  __shared__ bf16 lB[64 * 32];
  const int K = 2048;
  int bm = blockIdx.y, nb = blockIdx.x;
  int t = threadIdx.x;
  int lane = t & 63, w = t >> 6;
  int wm = (w >> 1) * 32, wn = (w & 1) * 32;
  int qd = lane >> 4, ln = lane & 15;

  f32x4 acc[2][2] = {};
  const bf16* Ab = A + (size_t)(bm * 64) * K;
  const bf16* Bb = Wvt + (size_t)(nb * 64) * K;

  int r = t >> 2, c = (t & 3) * 8;
  for (int kt = 0; kt < K; kt += 32) {
    GLDS16(&Ab[(size_t)r * K + kt + c], &lA[t * 8]);
    GLDS16(&Bb[(size_t)r * K + kt + c], &lB[t * 8]);
    __syncthreads();
    bf16x8 af[2], bfr[2];
    for (int i = 0; i < 2; ++i) af[i] = *(bf16x8*)&lA[(wm + i * 16 + ln) * 32 + qd * 8];
    for (int j = 0; j < 2; ++j) bfr[j] = *(bf16x8*)&lB[(wn + j * 16 + ln) * 32 + qd * 8];
    for (int i = 0; i < 2; ++i)
      for (int j = 0; j < 2; ++j)
        acc[i][j] = __builtin_amdgcn_mfma_f32_16x16x32_bf16(af[i], bfr[j], acc[i][j], 0, 0, 0);
    __syncthreads();
  }

  int b = bm >> 5;
  for (int j = 0; j < 2; ++j) {
    int n = nb * 64 + wn + j * 16 + ln;
    float bb = bvF[n];
    for (int i = 0; i < 2; ++i) {
      int lloc = (bm & 31) * 64 + wm + i * 16 + qd * 4;
      bf16 p4[4] __attribute__((aligned(8)));
      for (int rr = 0; rr < 4; ++rr) p4[rr] = __float2bfloat16(acc[i][j][rr] + bb);
      *(uint2*)&vcT[((size_t)(b * 512 + n)) * 2048 + lloc] = *(uint2*)p4;
    }
  }
}

// ---------------- output GEMM: d_out = attn @ Wot^T + boF (fp32 bias), K=512 ----------------
__global__ __launch_bounds__(256) void gemm_bias_out(const bf16* __restrict__ A,
                                                     const bf16* __restrict__ Bt,
                                                     const float* __restrict__ bias,
                                                     void* __restrict__ C,
                                                     int M, int N, int K,
                                                     const int* __restrict__ flagp) {
  __shared__ bf16 lA[128 * 32];
  __shared__ bf16 lB[128 * 32];
  int f32out = *flagp;
  int bm = blockIdx.y, bn = blockIdx.x;
  int t = threadIdx.x;
  int lane = t & 63, w = t >> 6;
  int wm = (w >> 1) * 64, wn = (w & 1) * 64;
  int qd = lane >> 4, ln = lane & 15;

  f32x4 acc[4][4] = {};
  const bf16* Ab = A + (size_t)(bm * 128) * K;
  const bf16* Bb = Bt + (size_t)(bn * 128) * K;

  for (int kt = 0; kt < K; kt += 32) {
    for (int p = 0; p < 2; ++p) {
      int slot = t + p * 256;
      int r = slot >> 2, c = (slot & 3) * 8;
      GLDS16(&Ab[(size_t)r * K + kt + c], &lA[slot * 8]);
      GLDS16(&Bb[(size_t)r * K + kt + c], &lB[slot * 8]);
    }
    __syncthreads();
    bf16x8 af[4], bfr[4];
    for (int i = 0; i < 4; ++i) af[i] = *(bf16x8*)&lA[(wm + i * 16 + ln) * 32 + qd * 8];
    for (int j = 0; j < 4; ++j) bfr[j] = *(bf16x8*)&lB[(wn + j * 16 + ln) * 32 + qd * 8];
    for (int i = 0; i < 4; ++i)
      for (int j = 0; j < 4; ++j)
        acc[i][j] = __builtin_amdgcn_mfma_f32_16x16x32_bf16(af[i], bfr[j], acc[i][j], 0, 0, 0);
    __syncthreads();
  }
  for (int i = 0; i < 4; ++i)
    for (int j = 0; j < 4; ++j) {
      int col = bn * 128 + wn + j * 16 + ln;
      float bv = bias[col];
      for (int r = 0; r < 4; ++r) {
        int row = bm * 128 + wm + i * 16 + qd * 4 + r;
        float v = acc[i][j][r] + bv;
        if (f32out) ((float*)C)[(size_t)row * N + col] = v;
        else ((bf16*)C)[(size_t)row * N + col] = __float2bfloat16(v);
      }
    }
}

// ---------------- flash attention (LD=32, causal); writes 512-wide attn ----------------
__global__ __launch_bounds__(256) void flash32(const bf16* __restrict__ qc,
                                               const bf16* __restrict__ kc,
                                               const bf16* __restrict__ vcT,
                                               bf16* __restrict__ attn) {
  __shared__ bf16 pbuf[4][16 * 40];
  int t = threadIdx.x;
  int lane = t & 63, w = t >> 6;
  int qd = lane >> 4, ln = lane & 15;
  int blk = blockIdx.x;
  int lt = blk & 31;
  int bh = blk >> 5, h = bh & 15, b = bh >> 4;
  int q0 = lt * 64 + w * 16;

  bf16x8 qf = *(const bf16x8*)&qc[((size_t)bh * Lseq + q0 + ln) * 32 + qd * 8];

  f32x4 o0 = {}, o1 = {};
  float m[4], lsum[4];
  for (int r = 0; r < 4; ++r) { m[r] = -1e30f; lsum[r] = 0.f; }
  const float scale = 0.17677669529663687f;  // 1/sqrt(32)

  int nkt = (q0 + 16 + 31) >> 5;
  bf16* pb = pbuf[w];
  for (int kt = 0; kt < nkt; ++kt) {
    int k0 = kt * 32;
    bf16x8 kf0 = *(const bf16x8*)&kc[((size_t)bh * Lseq + k0 + ln) * 32 + qd * 8];
    bf16x8 kf1 = *(const bf16x8*)&kc[((size_t)bh * Lseq + k0 + 16 + ln) * 32 + qd * 8];
    f32x4 s0 = {}, s1 = {};
    s0 = __builtin_amdgcn_mfma_f32_16x16x32_bf16(qf, kf0, s0, 0, 0, 0);
    s1 = __builtin_amdgcn_mfma_f32_16x16x32_bf16(qf, kf1, s1, 0, 0, 0);
    float sv0[4], sv1[4], alpha[4];
    for (int r = 0; r < 4; ++r) {
      int qrow = q0 + qd * 4 + r;
      sv0[r] = (k0 + ln <= qrow) ? s0[r] * scale : -1e30f;
      sv1[r] = (k0 + 16 + ln <= qrow) ? s1[r] * scale : -1e30f;
    }
    for (int r = 0; r < 4; ++r) {
      float mx = fmaxf(sv0[r], sv1[r]);
      for (int off = 1; off < 16; off <<= 1) mx = fmaxf(mx, __shfl_xor(mx, off, 64));
      float mn = fmaxf(m[r], mx);
      alpha[r] = __expf(m[r] - mn);
      m[r] = mn;
      sv0[r] = __expf(sv0[r] - mn);
      sv1[r] = __expf(sv1[r] - mn);
      float rs = sv0[r] + sv1[r];
      for (int off = 1; off < 16; off <<= 1) rs += __shfl_xor(rs, off, 64);
      lsum[r] = lsum[r] * alpha[r] + rs;
      o0[r] *= alpha[r];
      o1[r] *= alpha[r];
    }
    for (int r = 0; r < 4; ++r) {
      pb[(qd * 4 + r) * 40 + ln] = __float2bfloat16(sv0[r]);
      pb[(qd * 4 + r) * 40 + 16 + ln] = __float2bfloat16(sv1[r]);
    }
    asm volatile("s_waitcnt lgkmcnt(0)" ::: "memory");
    bf16x8 pf = *(bf16x8*)&pb[ln * 40 + qd * 8];
    bf16x8 vf0 = *(const bf16x8*)&vcT[((size_t)bh * 32 + ln) * Lseq + k0 + qd * 8];
    bf16x8 vf1 = *(const bf16x8*)&vcT[((size_t)bh * 32 + 16 + ln) * Lseq + k0 + qd * 8];
    o0 = __builtin_amdgcn_mfma_f32_16x16x32_bf16(pf, vf0, o0, 0, 0, 0);
    o1 = __builtin_amdgcn_mfma_f32_16x16x32_bf16(pf, vf1, o1, 0, 0, 0);
  }
  // epilogue: normalize, store 512-wide compressed attn (decompress folded into Wot)
  for (int r = 0; r < 4; ++r) {
    float inv = 1.0f / lsum[r];
    int l = q0 + qd * 4 + r;
    size_t base = ((size_t)(b * Lseq + l)) * 512 + h * 32;
    attn[base + ln] = __float2bfloat16(o0[r] * inv);
    attn[base + 16 + ln] = __float2bfloat16(o1[r] * inv);
  }
}

extern "C" void kernel_launch(void* const* d_in, const int* in_sizes, int n_in,
                              void* d_out, int out_size, void* d_ws, size_t ws_size,
                              hipStream_t stream) {
  const void* x = d_in[0];
  const void* cosS = d_in[1];
  const void* sinS = d_in[2];
  const void* Wq = d_in[3];
  const void* bq = d_in[4];
  const void* Wk = d_in[5];
  const void* bk = d_in[6];
  const void* Wv = d_in[7];
  const void* bv = d_in[8];
  const void* Wqc = d_in[9];
  const void* bqc = d_in[10];
  const void* Wkc = d_in[11];
  const void* bkc = d_in[12];
  const void* Wvc = d_in[13];
  const void* bvc = d_in[14];
  const void* Wd = d_in[15];
  const void* bd = d_in[16];
  const void* Wo = d_in[17];
  const void* bo = d_in[18];

  char* ws = (char*)d_ws;
  size_t off = 0;
  auto alloc = [&](size_t bytes) {
    char* p = ws + off;
    off += (bytes + 255) & ~(size_t)255;
    return p;
  };
  int* flag = (int*)alloc(256);
  bf16* small = (bf16*)alloc((size_t)SM_TOT * 2);
  bf16* wctG = (bf16*)alloc((size_t)12288 * 2);
  bf16* wdtG = (bf16*)alloc((size_t)4096 * 2);
  bf16* xb = (bf16*)alloc((size_t)4096 * 2048 * 2);
  bf16* WvB = (bf16*)alloc((size_t)2048 * 2048 * 2);
  bf16* WtQK = (bf16*)alloc((size_t)4096 * 2048 * 2);
  bf16* WtO = (bf16*)alloc((size_t)2048 * 2048 * 2);
  bf16* Wvt = (bf16*)alloc((size_t)512 * 2048 * 2);
  bf16* Wot = (bf16*)alloc((size_t)2048 * 512 * 2);
  float* bo_part = (float*)alloc((size_t)16 * 2048 * 4);
  float* boF = (float*)alloc((size_t)2048 * 4);
  float* bvF = (float*)alloc((size_t)512 * 4);
  bf16* qcW = (bf16*)alloc((size_t)65536 * 32 * 2);
  bf16* kcW = (bf16*)alloc((size_t)65536 * 32 * 2);
  bf16* vcTW = (bf16*)alloc((size_t)65536 * 32 * 2);
  bf16* attnW = (bf16*)alloc((size_t)4096 * 512 * 2);

  dim3 tb(256);
  detect_dtype<<<1, 64, 0, stream>>>((const ushort*)x, flag);
  prep<<<160, tb, 0, stream>>>(cosS, sinS, Wqc, Wkc, Wvc, bqc, bkc, bvc, Wd, bd, bo, bq,
                               bk, bv, small, wctG, wdtG, flag);
  transpose3<<<dim3(32, 32, 3), tb, 0, stream>>>(Wq, Wk, Wo, WtQK, WtO, flag);
  conv_x<<<4096, tb, 0, stream>>>(x, xb, flag);
  conv_x<<<2048, tb, 0, stream>>>(Wv, WvB, flag);
  fold_vw<<<dim3(16, 16), tb, 0, stream>>>(WvB, wctG, Wvt);
  fold_ow<<<dim3(16, 16), tb, 0, stream>>>(WtO, small, Wot);
  fold_bias_partial<<<dim3(16, 16), tb, 0, stream>>>(Wo, bd, bo_part, flag);
  fold_bias_final<<<10, tb, 0, stream>>>(bo, bo_part, bv, bvc, Wvc, boF, bvF, flag);
  gemm_v_fold<<<dim3(8, 64), tb, 0, stream>>>(xb, Wvt, bvF, vcTW);
  gemm_qk_compress<<<dim3(32, 32), tb, 0, stream>>>(xb, WtQK, small, wctG, qcW, kcW);
  flash32<<<1024, tb, 0, stream>>>(qcW, kcW, vcTW, attnW);
  gemm_bias_out<<<dim3(16, 32), tb, 0, stream>>>(attnW, Wot, boF, d_out, 4096, 2048,
                                                 512, flag);
}

// Round 4
// 429.652 us; speedup vs baseline: 1.7219x; 1.1121x over previous
//
#include <hip/hip_runtime.h>
#include <hip/hip_bf16.h>

// CausalMLA: B=2, L=2048, D=2048, H=16, HD=128, LD=32. Inputs fp32 or bf16
// (runtime-detected); pipeline bf16/MFMA; output dtype follows input.
// R4: RoPE+compress fused into QKV-GEMM epilogue.
// R5: algebraic folds — V compress folded into weights, decompress into Wo.
// R6: fold_bias parallelized (was 276us serial).
// R7: split QK-GEMM (lean, 72 VGPR) from V-fold GEMM (64x64 tile).
// R8: flash32 was latency-starved (Occ 18.8%, MfmaUtil 2.7%, 128us): causal
//     imbalance (1..33 KV iters/block) + tiny grid (1024) + 32 shuffles/iter.
//     Rewrite: 1 q-tile(16 rows)/block, 4 waves split KV range (flash-decode
//     merge via LDS), grid 4096; lsum deferred to per-lane accum + single
//     end reduce (deletes the per-iter sum shuffle chain).

#define Bsz 2
#define Lseq 2048
#define Dmod 2048
#define Hn 16
#define HDim 128
#define LDim 32

typedef __bf16 bf16x8 __attribute__((ext_vector_type(8)));
typedef float f32x4 __attribute__((ext_vector_type(4)));
typedef __hip_bfloat16 bf16;

#define GLDS16(g, l)                                                    \
  __builtin_amdgcn_global_load_lds(                                     \
      (const __attribute__((address_space(1))) unsigned int*)(g),       \
      (__attribute__((address_space(3))) unsigned int*)(l), 16, 0, 0)

// ---- small-constants area layout (bf16 element offsets inside `small`) ----
#define SM_COS 0
#define SM_SIN 131072
#define SM_WC 262144     // Wqc|Wkc|Wvc 3*4096
#define SM_BC 274432     // bqc|bkc|bvc 3*32
#define SM_WD 274528     // 4096 (row-major Wd[e][hd] — used by fold_ow)
#define SM_BD 278624     // 128
#define SM_BO 278752     // 2048
#define SM_BQKV 280800   // bq|bk|bv 3*2048
#define SM_TOT 286944

// ---------------- dtype detector ----------------
__global__ void detect_dtype(const ushort* __restrict__ x, int* __restrict__ flag) {
  int t = threadIdx.x;  // 64 threads
  int bad = 0;
  for (int k = 0; k < 4; ++k) {
    ushort u = x[t * 4 + k];
    int ex = (u >> 7) & 0xFF;
    if (ex >= 0xC0) bad = 1;
  }
  unsigned long long b = __ballot(bad);
  if (t == 0) *flag = (b != 0ULL) ? 1 : 0;  // 1 = inputs are fp32
}

__device__ inline void conv8(const void* src, size_t so, bf16* dst, size_t dof, int f32) {
  if (f32) {
    const float* s = (const float*)src + so;
    bf16 tmp[8] __attribute__((aligned(16)));
    for (int j = 0; j < 8; ++j) tmp[j] = __float2bfloat16(s[j]);
    *(uint4*)&dst[dof] = *(uint4*)tmp;
  } else {
    *(uint4*)&dst[dof] = *(const uint4*)((const ushort*)src + so);
  }
}

__device__ inline float cv1(const void* s, size_t i, int f32) {
  return f32 ? ((const float*)s)[i] : __bfloat162float(((const bf16*)s)[i]);
}

__global__ __launch_bounds__(256) void conv_x(const void* __restrict__ xs,
                                              bf16* __restrict__ xd,
                                              const int* __restrict__ flagp) {
  int f32 = *flagp;
  size_t e = ((size_t)blockIdx.x * 256 + threadIdx.x) * 8;
  conv8(xs, e, xd, e, f32);
}

// ---------------- prep: small-area conversion + wctG/wdtG ----------------
__global__ __launch_bounds__(256) void prep(
    const void* cosS, const void* sinS, const void* WqcS, const void* WkcS,
    const void* WvcS, const void* bqcS, const void* bkcS, const void* bvcS,
    const void* WdS, const void* bdS, const void* boS, const void* bqS,
    const void* bkS, const void* bvS, bf16* __restrict__ dst,
    bf16* __restrict__ wctG, bf16* __restrict__ wdtG,
    const int* __restrict__ flagp) {
  int f32 = *flagp;
  int tid = blockIdx.x * 256 + threadIdx.x;  // grid 160 -> 40960
  if (tid < SM_TOT / 8) {
    size_t e = (size_t)tid * 8;
    const void* src;
    size_t so;
    if (e < SM_SIN) { src = cosS; so = e - SM_COS; }
    else if (e < SM_WC) { src = sinS; so = e - SM_SIN; }
    else if (e < SM_BC) { size_t r = e - SM_WC; src = (r < 4096) ? WqcS : (r < 8192) ? WkcS : WvcS; so = r & 4095; }
    else if (e < SM_WD) { size_t r = e - SM_BC; src = (r < 32) ? bqcS : (r < 64) ? bkcS : bvcS; so = r & 31; }
    else if (e < SM_BD) { src = WdS; so = e - SM_WD; }
    else if (e < SM_BO) { src = bdS; so = e - SM_BD; }
    else if (e < SM_BQKV) { src = boS; so = e - SM_BO; }
    else { size_t r = e - SM_BQKV; src = (r < 2048) ? bqS : (r < 4096) ? bkS : bvS; so = r & 2047; }
    conv8(src, so, dst, e, f32);
  } else {
    int idx = tid - SM_TOT / 8;
    for (int i = idx; i < 16384; i += 40960 - SM_TOT / 8) {
      if (i < 12288) {
        int reg = i >> 12, rem = i & 4095, n = rem >> 7, k = rem & 127;
        const void* src = (reg == 0) ? WqcS : (reg == 1) ? WkcS : WvcS;
        wctG[i] = __float2bfloat16(cv1(src, (size_t)k * 32 + n, f32));
      } else {
        int i2 = i - 12288, o = i2 >> 5, e = i2 & 31;
        wdtG[i2] = __float2bfloat16(cv1(WdS, (size_t)e * 128 + o, f32));
      }
    }
  }
}

// ---------------- 3 weight transposes: Wt[n][k] = W[k][n] (Wq, Wk, Wo) ----------------
__global__ __launch_bounds__(256) void transpose3(const void* __restrict__ WqS,
                                                  const void* __restrict__ WkS,
                                                  const void* __restrict__ WoS,
                                                  bf16* __restrict__ WtQK,
                                                  bf16* __restrict__ WtO,
                                                  const int* __restrict__ flagp) {
  __shared__ float tile[64][65];
  int f32 = *flagp;
  int z = blockIdx.z;
  const void* W = (z == 0) ? WqS : (z == 1) ? WkS : WoS;
  bf16* Wt = (z == 2) ? WtO : (WtQK + (size_t)z * 2048 * 2048);
  int n0 = blockIdx.x * 64, k0 = blockIdx.y * 64;
  int t = threadIdx.x;
  int x = (t & 7) * 8, y = t >> 3;
  for (int p = 0; p < 2; ++p) {
    int r = y + p * 32;
    if (f32) {
      const float* src = (const float*)W + (size_t)(k0 + r) * 2048 + n0 + x;
      float4 a = *(const float4*)src;
      float4 b2 = *(const float4*)(src + 4);
      tile[r][x + 0] = a.x; tile[r][x + 1] = a.y; tile[r][x + 2] = a.z; tile[r][x + 3] = a.w;
      tile[r][x + 4] = b2.x; tile[r][x + 5] = b2.y; tile[r][x + 6] = b2.z; tile[r][x + 7] = b2.w;
    } else {
      const ushort* src = (const ushort*)W + (size_t)(k0 + r) * 2048 + n0 + x;
      uint4 u = *(const uint4*)src;
      bf16* e = (bf16*)&u;
      for (int j = 0; j < 8; ++j) tile[r][x + j] = __bfloat162float(e[j]);
    }
  }
  __syncthreads();
  for (int p = 0; p < 2; ++p) {
    int n = y + p * 32;
    bf16 tmp[8] __attribute__((aligned(16)));
    for (int j = 0; j < 8; ++j) tmp[j] = __float2bfloat16(tile[x + j][n]);
    *(uint4*)&Wt[(size_t)(n0 + n) * 2048 + k0 + x] = *(uint4*)tmp;
  }
}

// ---------------- fold_vw: W~vt[(h*32+e)][d_in] = sum_hd Wvc^T[e][hd] * Wv[d_in][128h+hd] ----------------
__global__ __launch_bounds__(256) void fold_vw(const bf16* __restrict__ WvB,
                                               const bf16* __restrict__ wctG,
                                               bf16* __restrict__ Wvt) {
  int nb = blockIdx.x, h = blockIdx.y;
  int t = threadIdx.x, lane = t & 63, w = t >> 6;
  int qd = lane >> 4, ln = lane & 15;
  f32x4 acc[2][2] = {};
  for (int kt = 0; kt < 4; ++kt) {
    bf16x8 af[2], bfr[2];
    for (int i = 0; i < 2; ++i)
      af[i] = *(const bf16x8*)&wctG[8192 + (i * 16 + ln) * 128 + kt * 32 + qd * 8];
    for (int j = 0; j < 2; ++j)
      bfr[j] = *(const bf16x8*)&WvB[(size_t)(nb * 128 + w * 32 + j * 16 + ln) * 2048 +
                                    h * 128 + kt * 32 + qd * 8];
    for (int i = 0; i < 2; ++i)
      for (int j = 0; j < 2; ++j)
        acc[i][j] = __builtin_amdgcn_mfma_f32_16x16x32_bf16(af[i], bfr[j], acc[i][j], 0, 0, 0);
  }
  for (int i = 0; i < 2; ++i)
    for (int j = 0; j < 2; ++j)
      for (int r = 0; r < 4; ++r) {
        int e = i * 16 + qd * 4 + r;
        int col = nb * 128 + w * 32 + j * 16 + ln;
        Wvt[(size_t)(h * 32 + e) * 2048 + col] = __float2bfloat16(acc[i][j][r]);
      }
}

// ---------------- fold_ow: W~ot[d_out][(h*32+e)] = sum_hd Wd[e][hd] * WtO[d_out][128h+hd] ----------------
__global__ __launch_bounds__(256) void fold_ow(const bf16* __restrict__ WtO,
                                               const bf16* __restrict__ small,
                                               bf16* __restrict__ Wot) {
  int mb = blockIdx.x, h = blockIdx.y;
  int t = threadIdx.x, lane = t & 63, w = t >> 6;
  int qd = lane >> 4, ln = lane & 15;
  f32x4 acc[2][2] = {};
  for (int kt = 0; kt < 4; ++kt) {
    bf16x8 af[2], bfr[2];
    for (int i = 0; i < 2; ++i)
      af[i] = *(const bf16x8*)&WtO[(size_t)(mb * 128 + w * 32 + i * 16 + ln) * 2048 +
                                   h * 128 + kt * 32 + qd * 8];
    for (int j = 0; j < 2; ++j)
      bfr[j] = *(const bf16x8*)&small[SM_WD + (j * 16 + ln) * 128 + kt * 32 + qd * 8];
    for (int i = 0; i < 2; ++i)
      for (int j = 0; j < 2; ++j)
        acc[i][j] = __builtin_amdgcn_mfma_f32_16x16x32_bf16(af[i], bfr[j], acc[i][j], 0, 0, 0);
  }
  for (int i = 0; i < 2; ++i)
    for (int j = 0; j < 2; ++j)
      for (int r = 0; r < 4; ++r) {
        int row = mb * 128 + w * 32 + i * 16 + qd * 4 + r;
        int col = h * 32 + j * 16 + ln;
        Wot[(size_t)row * 512 + col] = __float2bfloat16(acc[i][j][r]);
      }
}

// ---------------- fold_bias stage 1 ----------------
__global__ __launch_bounds__(256) void fold_bias_partial(const void* WoS, const void* bdS,
                                                         float* __restrict__ bo_part,
                                                         const int* __restrict__ flagp) {
  __shared__ float red[256];
  int f32 = *flagp;
  int nb = blockIdx.x, kb = blockIdx.y;
  int t = threadIdx.x;
  int col = nb * 128 + (t & 127);
  int half = t >> 7;
  float s = 0.f;
  int kbase = kb * 128 + half * 64;
  for (int i = 0; i < 64; ++i) {
    int k = kbase + i;
    s += cv1(bdS, k & 127, f32) * cv1(WoS, (size_t)k * 2048 + col, f32);
  }
  red[t] = s;
  __syncthreads();
  if (half == 0) bo_part[kb * 2048 + col] = red[t] + red[t + 128];
}

// ---------------- fold_bias stage 2 ----------------
__global__ __launch_bounds__(256) void fold_bias_final(const void* boS,
                                                       const float* __restrict__ bo_part,
                                                       const void* bvS, const void* bvcS,
                                                       const void* WvcS,
                                                       float* __restrict__ boF,
                                                       float* __restrict__ bvF,
                                                       const int* __restrict__ flagp) {
  int f32 = *flagp;
  int tid = blockIdx.x * 256 + threadIdx.x;  // grid 10 -> 2560
  if (tid < 2048) {
    float s = cv1(boS, tid, f32);
    for (int kb = 0; kb < 16; ++kb) s += bo_part[kb * 2048 + tid];
    boF[tid] = s;
  } else if (tid < 2560) {
    int j = tid - 2048, h = j >> 5, e = j & 31;
    float s = cv1(bvcS, e, f32);
    for (int hd = 0; hd < 128; ++hd)
      s += cv1(bvS, h * 128 + hd, f32) * cv1(WvcS, (size_t)hd * 32 + e, f32);
    bvF[j] = s;
  }
}

// ---------------- QK GEMM + fused RoPE + compression (bn 0..31) ----------------
#define ESTR 136
__global__ __launch_bounds__(256) void gemm_qk_compress(
    const bf16* __restrict__ A, const bf16* __restrict__ Bt,
    const bf16* __restrict__ small, const bf16* __restrict__ wctG,
    bf16* __restrict__ qc, bf16* __restrict__ kc) {
  __shared__ bf16 sh[128 * ESTR];  // 34816 B; first 16KB doubles as lA|lB
  bf16* lA = sh;
  bf16* lB = sh + 4096;
  const int K = 2048;
  int bm = blockIdx.y, bn = blockIdx.x;
  int reg = bn >> 4, h = bn & 15;
  int t = threadIdx.x;
  int lane = t & 63, w = t >> 6;
  int wm = (w >> 1) * 64, wn = (w & 1) * 64;
  int qd = lane >> 4, ln = lane & 15;

  f32x4 acc[4][4] = {};
  const bf16* Ab = A + (size_t)(bm * 128) * K;
  const bf16* Bb = Bt + (size_t)(bn * 128) * K;

  for (int kt = 0; kt < K; kt += 32) {
    for (int p = 0; p < 2; ++p) {
      int slot = t + p * 256;
      int r = slot >> 2, c = (slot & 3) * 8;
      GLDS16(&Ab[(size_t)r * K + kt + c], &lA[slot * 8]);
      GLDS16(&Bb[(size_t)r * K + kt + c], &lB[slot * 8]);
    }
    __syncthreads();
    bf16x8 af[4], bfr[4];
    for (int i = 0; i < 4; ++i) af[i] = *(bf16x8*)&lA[(wm + i * 16 + ln) * 32 + qd * 8];
    for (int j = 0; j < 4; ++j) bfr[j] = *(bf16x8*)&lB[(wn + j * 16 + ln) * 32 + qd * 8];
    for (int i = 0; i < 4; ++i)
      for (int j = 0; j < 4; ++j)
        acc[i][j] = __builtin_amdgcn_mfma_f32_16x16x32_bf16(af[i], bfr[j], acc[i][j], 0, 0, 0);
    __syncthreads();
  }

  // epilogue 1: acc + bias -> LDS tile (row = block-local l, col = head dim)
  for (int j = 0; j < 4; ++j) {
    int col = wn + j * 16 + ln;
    float bv = __bfloat162float(small[SM_BQKV + bn * 128 + col]);
    for (int i = 0; i < 4; ++i)
      for (int r = 0; r < 4; ++r)
        sh[(wm + i * 16 + qd * 4 + r) * ESTR + col] = __float2bfloat16(acc[i][j][r] + bv);
  }
  __syncthreads();

  // epilogue 2: RoPE + compress 32 l-rows per wave
  int r0 = w * 32;
  int b = bm >> 4;
  int bh = b * Hn + h;
  bf16x8 bfr2[2][4];
  for (int nt = 0; nt < 2; ++nt)
    for (int kt = 0; kt < 4; ++kt)
      bfr2[nt][kt] = *(const bf16x8*)&wctG[reg * 4096 + (nt * 16 + ln) * 128 + kt * 32 + qd * 8];
  float bc[2];
  bc[0] = __bfloat162float(small[SM_BC + reg * 32 + ln]);
  bc[1] = __bfloat162float(small[SM_BC + reg * 32 + 16 + ln]);

  for (int mt = 0; mt < 2; ++mt) {
    int lb = r0 + mt * 16 + ln;
    int lg = (bm & 15) * 128 + lb;
    f32x4 c2[2] = {};
    for (int kt = 0; kt < 4; ++kt) {
      uint4 u = *(uint4*)&sh[lb * ESTR + kt * 32 + qd * 8];
      bf16* e8 = (bf16*)&u;
      int pbase = kt * 16 + qd * 4;
      for (int j = 0; j < 4; ++j) {
        float cvv = __bfloat162float(small[SM_COS + (size_t)lg * 64 + pbase + j]);
        float svv = __bfloat162float(small[SM_SIN + (size_t)lg * 64 + pbase + j]);
        float ev = __bfloat162float(e8[2 * j]);
        float ov = __bfloat162float(e8[2 * j + 1]);
        e8[2 * j] = __float2bfloat16(ev * cvv - ov * svv);
        e8[2 * j + 1] = __float2bfloat16(ev * svv + ov * cvv);
      }
      bf16x8 a = *(bf16x8*)&u;
      c2[0] = __builtin_amdgcn_mfma_f32_16x16x32_bf16(a, bfr2[0][kt], c2[0], 0, 0, 0);
      c2[1] = __builtin_amdgcn_mfma_f32_16x16x32_bf16(a, bfr2[1][kt], c2[1], 0, 0, 0);
    }
    int lgbase = (bm & 15) * 128 + r0 + mt * 16 + qd * 4;
    bf16* dst = (reg == 0) ? qc : kc;
    for (int nt = 0; nt < 2; ++nt)
      for (int r = 0; r < 4; ++r)
        dst[((size_t)bh * Lseq + lgbase + r) * 32 + nt * 16 + ln] =
            __float2bfloat16(c2[nt][r] + bc[nt]);
  }
}

// ---------------- V-fold GEMM: vcT[(b*512+n)][l] = x @ W~vt^T + bvF ----------------
__global__ __launch_bounds__(256) void gemm_v_fold(const bf16* __restrict__ A,
                                                   const bf16* __restrict__ Wvt,
                                                   const float* __restrict__ bvF,
                                                   bf16* __restrict__ vcT) {
  __shared__ bf16 lA[64 * 32];
  __shared__ bf16 lB[64 * 32];
  const int K = 2048;
  int bm = blockIdx.y, nb = blockIdx.x;
  int t = threadIdx.x;
  int lane = t & 63, w = t >> 6;
  int wm = (w >> 1) * 32, wn = (w & 1) * 32;
  int qd = lane >> 4, ln = lane & 15;

  f32x4 acc[2][2] = {};
  const bf16* Ab = A + (size_t)(bm * 64) * K;
  const bf16* Bb = Wvt + (size_t)(nb * 64) * K;

  int r = t >> 2, c = (t & 3) * 8;
  for (int kt = 0; kt < K; kt += 32) {
    GLDS16(&Ab[(size_t)r * K + kt + c], &lA[t * 8]);
    GLDS16(&Bb[(size_t)r * K + kt + c], &lB[t * 8]);
    __syncthreads();
    bf16x8 af[2], bfr[2];
    for (int i = 0; i < 2; ++i) af[i] = *(bf16x8*)&lA[(wm + i * 16 + ln) * 32 + qd * 8];
    for (int j = 0; j < 2; ++j) bfr[j] = *(bf16x8*)&lB[(wn + j * 16 + ln) * 32 + qd * 8];
    for (int i = 0; i < 2; ++i)
      for (int j = 0; j < 2; ++j)
        acc[i][j] = __builtin_amdgcn_mfma_f32_16x16x32_bf16(af[i], bfr[j], acc[i][j], 0, 0, 0);
    __syncthreads();
  }

  int b = bm >> 5;
  for (int j = 0; j < 2; ++j) {
    int n = nb * 64 + wn + j * 16 + ln;
    float bb = bvF[n];
    for (int i = 0; i < 2; ++i) {
      int lloc = (bm & 31) * 64 + wm + i * 16 + qd * 4;
      bf16 p4[4] __attribute__((aligned(8)));
      for (int rr = 0; rr < 4; ++rr) p4[rr] = __float2bfloat16(acc[i][j][rr] + bb);
      *(uint2*)&vcT[((size_t)(b * 512 + n)) * 2048 + lloc] = *(uint2*)p4;
    }
  }
}

// ---------------- output GEMM: d_out = attn @ Wot^T + boF (fp32 bias), K=512 ----------------
__global__ __launch_bounds__(256) void gemm_bias_out(const bf16* __restrict__ A,
                                                     const bf16* __restrict__ Bt,
                                                     const float* __restrict__ bias,
                                                     void* __restrict__ C,
                                                     int M, int N, int K,
                                                     const int* __restrict__ flagp) {
  __shared__ bf16 lA[128 * 32];
  __shared__ bf16 lB[128 * 32];
  int f32out = *flagp;
  int bm = blockIdx.y, bn = blockIdx.x;
  int t = threadIdx.x;
  int lane = t & 63, w = t >> 6;
  int wm = (w >> 1) * 64, wn = (w & 1) * 64;
  int qd = lane >> 4, ln = lane & 15;

  f32x4 acc[4][4] = {};
  const bf16* Ab = A + (size_t)(bm * 128) * K;
  const bf16* Bb = Bt + (size_t)(bn * 128) * K;

  for (int kt = 0; kt < K; kt += 32) {
    for (int p = 0; p < 2; ++p) {
      int slot = t + p * 256;
      int r = slot >> 2, c = (slot & 3) * 8;
      GLDS16(&Ab[(size_t)r * K + kt + c], &lA[slot * 8]);
      GLDS16(&Bb[(size_t)r * K + kt + c], &lB[slot * 8]);
    }
    __syncthreads();
    bf16x8 af[4], bfr[4];
    for (int i = 0; i < 4; ++i) af[i] = *(bf16x8*)&lA[(wm + i * 16 + ln) * 32 + qd * 8];
    for (int j = 0; j < 4; ++j) bfr[j] = *(bf16x8*)&lB[(wn + j * 16 + ln) * 32 + qd * 8];
    for (int i = 0; i < 4; ++i)
      for (int j = 0; j < 4; ++j)
        acc[i][j] = __builtin_amdgcn_mfma_f32_16x16x32_bf16(af[i], bfr[j], acc[i][j], 0, 0, 0);
    __syncthreads();
  }
  for (int i = 0; i < 4; ++i)
    for (int j = 0; j < 4; ++j) {
      int col = bn * 128 + wn + j * 16 + ln;
      float bv = bias[col];
      for (int r = 0; r < 4; ++r) {
        int row = bm * 128 + wm + i * 16 + qd * 4 + r;
        float v = acc[i][j][r] + bv;
        if (f32out) ((float*)C)[(size_t)row * N + col] = v;
        else ((bf16*)C)[(size_t)row * N + col] = __float2bfloat16(v);
      }
    }
}

// ---------------- flash attention R8: 1 q-tile(16)/block, 4-wave KV split + merge ----------------
__global__ __launch_bounds__(256) void flash32(const bf16* __restrict__ qc,
                                               const bf16* __restrict__ kc,
                                               const bf16* __restrict__ vcT,
                                               bf16* __restrict__ attn) {
  __shared__ bf16 pbuf[4][16 * 40];     // 5120 B
  __shared__ float oL[4][16][33];       // 8448 B (pad 33)
  __shared__ float mL[4][16];           // 256 B
  __shared__ float lsL[4][16];          // 256 B
  int t = threadIdx.x;
  int lane = t & 63, w = t >> 6;
  int qd = lane >> 4, ln = lane & 15;
  int blk = blockIdx.x;                 // grid 4096 = 32 bh x 128 q-tiles
  int j = blk & 127;
  int bh = blk >> 7, h = bh & 15, b = bh >> 4;
  int q0 = j * 16;

  bf16x8 qf = *(const bf16x8*)&qc[((size_t)bh * Lseq + q0 + ln) * 32 + qd * 8];

  f32x4 o0 = {}, o1 = {};
  float m[4], ls[4];
  for (int r = 0; r < 4; ++r) { m[r] = -1e30f; ls[r] = 0.f; }
  const float scale = 0.17677669529663687f;  // 1/sqrt(32)

  int nkt = (16 * j + 47) >> 5;         // causal KV chunks of 32
  int nw = (nkt + 3) >> 2;
  int kt0 = w * nw;
  int kt1 = min(kt0 + nw, nkt);

  bf16* pb = pbuf[w];
  for (int kt = kt0; kt < kt1; ++kt) {
    int k0 = kt * 32;
    bf16x8 kf0 = *(const bf16x8*)&kc[((size_t)bh * Lseq + k0 + ln) * 32 + qd * 8];
    bf16x8 kf1 = *(const bf16x8*)&kc[((size_t)bh * Lseq + k0 + 16 + ln) * 32 + qd * 8];
    f32x4 s0 = {}, s1 = {};
    s0 = __builtin_amdgcn_mfma_f32_16x16x32_bf16(qf, kf0, s0, 0, 0, 0);
    s1 = __builtin_amdgcn_mfma_f32_16x16x32_bf16(qf, kf1, s1, 0, 0, 0);
    float sv0[4], sv1[4], alpha[4];
    for (int r = 0; r < 4; ++r) {
      int qrow = q0 + qd * 4 + r;
      sv0[r] = (k0 + ln <= qrow) ? s0[r] * scale : -1e30f;
      sv1[r] = (k0 + 16 + ln <= qrow) ? s1[r] * scale : -1e30f;
    }
    for (int r = 0; r < 4; ++r) {
      float mx = fmaxf(sv0[r], sv1[r]);
      for (int off = 1; off < 16; off <<= 1) mx = fmaxf(mx, __shfl_xor(mx, off, 64));
      float mn = fmaxf(m[r], mx);
      alpha[r] = __expf(m[r] - mn);
      m[r] = mn;
      sv0[r] = __expf(sv0[r] - mn);
      sv1[r] = __expf(sv1[r] - mn);
      ls[r] = ls[r] * alpha[r] + sv0[r] + sv1[r];  // per-lane partial sum
      o0[r] *= alpha[r];
      o1[r] *= alpha[r];
    }
    for (int r = 0; r < 4; ++r) {
      pb[(qd * 4 + r) * 40 + ln] = __float2bfloat16(sv0[r]);
      pb[(qd * 4 + r) * 40 + 16 + ln] = __float2bfloat16(sv1[r]);
    }
    asm volatile("s_waitcnt lgkmcnt(0)" ::: "memory");
    bf16x8 pf = *(bf16x8*)&pb[ln * 40 + qd * 8];
    bf16x8 vf0 = *(const bf16x8*)&vcT[((size_t)bh * 32 + ln) * Lseq + k0 + qd * 8];
    bf16x8 vf1 = *(const bf16x8*)&vcT[((size_t)bh * 32 + 16 + ln) * Lseq + k0 + qd * 8];
    o0 = __builtin_amdgcn_mfma_f32_16x16x32_bf16(pf, vf0, o0, 0, 0, 0);
    o1 = __builtin_amdgcn_mfma_f32_16x16x32_bf16(pf, vf1, o1, 0, 0, 0);
  }

  // end-of-chunk: reduce per-lane lsum across the 16-lane group (once, not per iter)
  for (int r = 0; r < 4; ++r)
    for (int off = 1; off < 16; off <<= 1) ls[r] += __shfl_xor(ls[r], off, 64);

  // write partials to LDS
  for (int r = 0; r < 4; ++r) {
    int row = qd * 4 + r;
    oL[w][row][ln] = o0[r];
    oL[w][row][16 + ln] = o1[r];
    if (ln == 0) { mL[w][row] = m[r]; lsL[w][row] = ls[r]; }
  }
  __syncthreads();

  // merge 4 wave-partials (flash-decode combine), 512 outputs over 256 threads
  for (int idx = t; idx < 512; idx += 256) {
    int row = idx >> 5, col = idx & 31;
    float m0 = mL[0][row], m1 = mL[1][row], m2 = mL[2][row], m3 = mL[3][row];
    float ms = fmaxf(fmaxf(m0, m1), fmaxf(m2, m3));
    float e0 = __expf(m0 - ms), e1 = __expf(m1 - ms);
    float e2 = __expf(m2 - ms), e3 = __expf(m3 - ms);
    float lsum = lsL[0][row] * e0 + lsL[1][row] * e1 + lsL[2][row] * e2 + lsL[3][row] * e3;
    float val = oL[0][row][col] * e0 + oL[1][row][col] * e1 +
                oL[2][row][col] * e2 + oL[3][row][col] * e3;
    int l = q0 + row;
    attn[((size_t)(b * Lseq + l)) * 512 + h * 32 + col] = __float2bfloat16(val / lsum);
  }
}

extern "C" void kernel_launch(void* const* d_in, const int* in_sizes, int n_in,
                              void* d_out, int out_size, void* d_ws, size_t ws_size,
                              hipStream_t stream) {
  const void* x = d_in[0];
  const void* cosS = d_in[1];
  const void* sinS = d_in[2];
  const void* Wq = d_in[3];
  const void* bq = d_in[4];
  const void* Wk = d_in[5];
  const void* bk = d_in[6];
  const void* Wv = d_in[7];
  const void* bv = d_in[8];
  const void* Wqc = d_in[9];
  const void* bqc = d_in[10];
  const void* Wkc = d_in[11];
  const void* bkc = d_in[12];
  const void* Wvc = d_in[13];
  const void* bvc = d_in[14];
  const void* Wd = d_in[15];
  const void* bd = d_in[16];
  const void* Wo = d_in[17];
  const void* bo = d_in[18];

  char* ws = (char*)d_ws;
  size_t off = 0;
  auto alloc = [&](size_t bytes) {
    char* p = ws + off;
    off += (bytes + 255) & ~(size_t)255;
    return p;
  };
  int* flag = (int*)alloc(256);
  bf16* small = (bf16*)alloc((size_t)SM_TOT * 2);
  bf16* wctG = (bf16*)alloc((size_t)12288 * 2);
  bf16* wdtG = (bf16*)alloc((size_t)4096 * 2);
  bf16* xb = (bf16*)alloc((size_t)4096 * 2048 * 2);
  bf16* WvB = (bf16*)alloc((size_t)2048 * 2048 * 2);
  bf16* WtQK = (bf16*)alloc((size_t)4096 * 2048 * 2);
  bf16* WtO = (bf16*)alloc((size_t)2048 * 2048 * 2);
  bf16* Wvt = (bf16*)alloc((size_t)512 * 2048 * 2);
  bf16* Wot = (bf16*)alloc((size_t)2048 * 512 * 2);
  float* bo_part = (float*)alloc((size_t)16 * 2048 * 4);
  float* boF = (float*)alloc((size_t)2048 * 4);
  float* bvF = (float*)alloc((size_t)512 * 4);
  bf16* qcW = (bf16*)alloc((size_t)65536 * 32 * 2);
  bf16* kcW = (bf16*)alloc((size_t)65536 * 32 * 2);
  bf16* vcTW = (bf16*)alloc((size_t)65536 * 32 * 2);
  bf16* attnW = (bf16*)alloc((size_t)4096 * 512 * 2);

  dim3 tb(256);
  detect_dtype<<<1, 64, 0, stream>>>((const ushort*)x, flag);
  prep<<<160, tb, 0, stream>>>(cosS, sinS, Wqc, Wkc, Wvc, bqc, bkc, bvc, Wd, bd, bo, bq,
                               bk, bv, small, wctG, wdtG, flag);
  transpose3<<<dim3(32, 32, 3), tb, 0, stream>>>(Wq, Wk, Wo, WtQK, WtO, flag);
  conv_x<<<4096, tb, 0, stream>>>(x, xb, flag);
  conv_x<<<2048, tb, 0, stream>>>(Wv, WvB, flag);
  fold_vw<<<dim3(16, 16), tb, 0, stream>>>(WvB, wctG, Wvt);
  fold_ow<<<dim3(16, 16), tb, 0, stream>>>(WtO, small, Wot);
  fold_bias_partial<<<dim3(16, 16), tb, 0, stream>>>(Wo, bd, bo_part, flag);
  fold_bias_final<<<10, tb, 0, stream>>>(bo, bo_part, bv, bvc, Wvc, boF, bvF, flag);
  gemm_v_fold<<<dim3(8, 64), tb, 0, stream>>>(xb, Wvt, bvF, vcTW);
  gemm_qk_compress<<<dim3(32, 32), tb, 0, stream>>>(xb, WtQK, small, wctG, qcW, kcW);
  flash32<<<4096, tb, 0, stream>>>(qcW, kcW, vcTW, attnW);
  gemm_bias_out<<<dim3(16, 32), tb, 0, stream>>>(attnW, Wot, boF, d_out, 4096, 2048,
                                                 512, flag);
}

// Round 5
// 409.089 us; speedup vs baseline: 1.8084x; 1.0503x over previous
//
#include <hip/hip_runtime.h>
#include <hip/hip_bf16.h>

// CausalMLA: B=2, L=2048, D=2048, H=16, HD=128, LD=32. Inputs fp32 or bf16
// (runtime-detected); pipeline bf16/MFMA; output dtype follows input.
// R4: RoPE+compress fused into QKV-GEMM epilogue.
// R5: algebraic folds — V compress folded into weights, decompress into Wo.
// R6: fold_bias parallelized (was 276us serial).
// R7: split QK-GEMM (lean, 72 VGPR) from V-fold GEMM (64x64 tile).
// R8: flash32: 1 q-tile/block, 4-wave KV split + flash-decode merge.
// R9: (a) prep stage fused: 13 -> 7 dispatches (prep_all: transpose3 +
//     conv Wv + conv x + small-prep + fold_bias_partial in one z-switched
//     grid; fold_all: fold_vw + fold_ow + fold_bias_final). (b) flash32
//     processes 64 keys/iter -> half the serial max-shuffle chains.
//     (c) gemm_qk: bijective XCD swizzle (4 bm-rows contiguous per XCD)
//     for L2-resident A panels.

#define Bsz 2
#define Lseq 2048
#define Dmod 2048
#define Hn 16
#define HDim 128
#define LDim 32

typedef __bf16 bf16x8 __attribute__((ext_vector_type(8)));
typedef float f32x4 __attribute__((ext_vector_type(4)));
typedef __hip_bfloat16 bf16;

#define GLDS16(g, l)                                                    \
  __builtin_amdgcn_global_load_lds(                                     \
      (const __attribute__((address_space(1))) unsigned int*)(g),       \
      (__attribute__((address_space(3))) unsigned int*)(l), 16, 0, 0)

// ---- small-constants area layout (bf16 element offsets inside `small`) ----
#define SM_COS 0
#define SM_SIN 131072
#define SM_WC 262144     // Wqc|Wkc|Wvc 3*4096
#define SM_BC 274432     // bqc|bkc|bvc 3*32
#define SM_WD 274528     // 4096 (row-major Wd[e][hd] — used by fold_ow)
#define SM_BD 278624     // 128
#define SM_BO 278752     // 2048
#define SM_BQKV 280800   // bq|bk|bv 3*2048
#define SM_TOT 286944

// ---------------- dtype detector ----------------
__global__ void detect_dtype(const ushort* __restrict__ x, int* __restrict__ flag) {
  int t = threadIdx.x;  // 64 threads
  int bad = 0;
  for (int k = 0; k < 4; ++k) {
    ushort u = x[t * 4 + k];
    int ex = (u >> 7) & 0xFF;
    if (ex >= 0xC0) bad = 1;
  }
  unsigned long long b = __ballot(bad);
  if (t == 0) *flag = (b != 0ULL) ? 1 : 0;  // 1 = inputs are fp32
}

__device__ inline void conv8(const void* src, size_t so, bf16* dst, size_t dof, int f32) {
  if (f32) {
    const float* s = (const float*)src + so;
    bf16 tmp[8] __attribute__((aligned(16)));
    for (int j = 0; j < 8; ++j) tmp[j] = __float2bfloat16(s[j]);
    *(uint4*)&dst[dof] = *(uint4*)tmp;
  } else {
    *(uint4*)&dst[dof] = *(const uint4*)((const ushort*)src + so);
  }
}

__device__ inline float cv1(const void* s, size_t i, int f32) {
  return f32 ? ((const float*)s)[i] : __bfloat162float(((const bf16*)s)[i]);
}

// ---------------- prep_all: transpose3 | conv Wv | conv x | small-prep | fbp ----------------
#define NB_T3 3072
#define NB_WV 2048
#define NB_CX 4096
#define NB_PREP 160
#define NB_FBP 256
#define NB_PREP_ALL (NB_T3 + NB_WV + NB_CX + NB_PREP + NB_FBP)  // 9632

__global__ __launch_bounds__(256) void prep_all(
    const void* xS, const void* cosS, const void* sinS, const void* WqS,
    const void* WkS, const void* WvS, const void* WoS, const void* WqcS,
    const void* WkcS, const void* WvcS, const void* bqcS, const void* bkcS,
    const void* bvcS, const void* WdS, const void* bdS, const void* boS,
    const void* bqS, const void* bkS, const void* bvS,
    bf16* __restrict__ xb, bf16* __restrict__ WvB, bf16* __restrict__ WtQK,
    bf16* __restrict__ WtO, bf16* __restrict__ small, bf16* __restrict__ wctG,
    bf16* __restrict__ wdtG, float* __restrict__ bo_part,
    const int* __restrict__ flagp) {
  __shared__ __align__(16) char shm[16640];
  int f32 = *flagp;
  int blk = blockIdx.x;
  int t = threadIdx.x;

  if (blk < NB_T3) {
    // --- weight transpose (Wq, Wk, Wo) ---
    float (*tile)[65] = (float(*)[65])shm;
    int z = blk >> 10, rem = blk & 1023;
    const void* W = (z == 0) ? WqS : (z == 1) ? WkS : WoS;
    bf16* Wt = (z == 2) ? WtO : (WtQK + (size_t)z * 2048 * 2048);
    int n0 = (rem & 31) * 64, k0 = (rem >> 5) * 64;
    int x = (t & 7) * 8, y = t >> 3;
    for (int p = 0; p < 2; ++p) {
      int r = y + p * 32;
      if (f32) {
        const float* src = (const float*)W + (size_t)(k0 + r) * 2048 + n0 + x;
        float4 a = *(const float4*)src;
        float4 b2 = *(const float4*)(src + 4);
        tile[r][x + 0] = a.x; tile[r][x + 1] = a.y; tile[r][x + 2] = a.z; tile[r][x + 3] = a.w;
        tile[r][x + 4] = b2.x; tile[r][x + 5] = b2.y; tile[r][x + 6] = b2.z; tile[r][x + 7] = b2.w;
      } else {
        const ushort* src = (const ushort*)W + (size_t)(k0 + r) * 2048 + n0 + x;
        uint4 u = *(const uint4*)src;
        bf16* e = (bf16*)&u;
        for (int jj = 0; jj < 8; ++jj) tile[r][x + jj] = __bfloat162float(e[jj]);
      }
    }
    __syncthreads();
    for (int p = 0; p < 2; ++p) {
      int n = y + p * 32;
      bf16 tmp[8] __attribute__((aligned(16)));
      for (int jj = 0; jj < 8; ++jj) tmp[jj] = __float2bfloat16(tile[x + jj][n]);
      *(uint4*)&Wt[(size_t)(n0 + n) * 2048 + k0 + x] = *(uint4*)tmp;
    }
  } else if (blk < NB_T3 + NB_WV) {
    // --- Wv -> bf16 copy ---
    size_t e = ((size_t)(blk - NB_T3) * 256 + t) * 8;
    conv8(WvS, e, WvB, e, f32);
  } else if (blk < NB_T3 + NB_WV + NB_CX) {
    // --- x -> bf16 copy ---
    size_t e = ((size_t)(blk - NB_T3 - NB_WV) * 256 + t) * 8;
    conv8(xS, e, xb, e, f32);
  } else if (blk < NB_T3 + NB_WV + NB_CX + NB_PREP) {
    // --- small-area + wctG/wdtG prep ---
    int tid = (blk - NB_T3 - NB_WV - NB_CX) * 256 + t;  // 0..40959
    if (tid < SM_TOT / 8) {
      size_t e = (size_t)tid * 8;
      const void* src;
      size_t so;
      if (e < SM_SIN) { src = cosS; so = e - SM_COS; }
      else if (e < SM_WC) { src = sinS; so = e - SM_SIN; }
      else if (e < SM_BC) { size_t r = e - SM_WC; src = (r < 4096) ? WqcS : (r < 8192) ? WkcS : WvcS; so = r & 4095; }
      else if (e < SM_WD) { size_t r = e - SM_BC; src = (r < 32) ? bqcS : (r < 64) ? bkcS : bvcS; so = r & 31; }
      else if (e < SM_BD) { src = WdS; so = e - SM_WD; }
      else if (e < SM_BO) { src = bdS; so = e - SM_BD; }
      else if (e < SM_BQKV) { src = boS; so = e - SM_BO; }
      else { size_t r = e - SM_BQKV; src = (r < 2048) ? bqS : (r < 4096) ? bkS : bvS; so = r & 2047; }
      conv8(src, so, small, e, f32);
    } else {
      int idx = tid - SM_TOT / 8;
      for (int i = idx; i < 16384; i += 40960 - SM_TOT / 8) {
        if (i < 12288) {
          int reg = i >> 12, rem2 = i & 4095, n = rem2 >> 7, k = rem2 & 127;
          const void* src = (reg == 0) ? WqcS : (reg == 1) ? WkcS : WvcS;
          wctG[i] = __float2bfloat16(cv1(src, (size_t)k * 32 + n, f32));
        } else {
          int i2 = i - 12288, o = i2 >> 5, e = i2 & 31;
          wdtG[i2] = __float2bfloat16(cv1(WdS, (size_t)e * 128 + o, f32));
        }
      }
    }
  } else {
    // --- fold_bias partial: bo_part[kb][col] ---
    float* red = (float*)shm;
    int rem = blk - (NB_T3 + NB_WV + NB_CX + NB_PREP);
    int nb = rem & 15, kb = rem >> 4;
    int col = nb * 128 + (t & 127);
    int half = t >> 7;
    float s = 0.f;
    int kbase = kb * 128 + half * 64;
    for (int i = 0; i < 64; ++i) {
      int k = kbase + i;
      s += cv1(bdS, k & 127, f32) * cv1(WoS, (size_t)k * 2048 + col, f32);
    }
    red[t] = s;
    __syncthreads();
    if (half == 0) bo_part[kb * 2048 + col] = red[t] + red[t + 128];
  }
}

// ---------------- fold_all: fold_vw | fold_ow | fold_bias_final ----------------
__global__ __launch_bounds__(256) void fold_all(
    const bf16* __restrict__ WvB, const bf16* __restrict__ wctG,
    const bf16* __restrict__ WtO, const bf16* __restrict__ small,
    const void* boS, const float* __restrict__ bo_part, const void* bvS,
    const void* bvcS, const void* WvcS, bf16* __restrict__ Wvt,
    bf16* __restrict__ Wot, float* __restrict__ boF, float* __restrict__ bvF,
    const int* __restrict__ flagp) {
  int blk = blockIdx.x;
  int t = threadIdx.x, lane = t & 63, w = t >> 6;
  int qd = lane >> 4, ln = lane & 15;
  if (blk < 256) {
    // fold_vw: W~vt[(h*32+e)][d_in]
    int nb = blk & 15, h = blk >> 4;
    f32x4 acc[2][2] = {};
    for (int kt = 0; kt < 4; ++kt) {
      bf16x8 af[2], bfr[2];
      for (int i = 0; i < 2; ++i)
        af[i] = *(const bf16x8*)&wctG[8192 + (i * 16 + ln) * 128 + kt * 32 + qd * 8];
      for (int j = 0; j < 2; ++j)
        bfr[j] = *(const bf16x8*)&WvB[(size_t)(nb * 128 + w * 32 + j * 16 + ln) * 2048 +
                                      h * 128 + kt * 32 + qd * 8];
      for (int i = 0; i < 2; ++i)
        for (int j = 0; j < 2; ++j)
          acc[i][j] = __builtin_amdgcn_mfma_f32_16x16x32_bf16(af[i], bfr[j], acc[i][j], 0, 0, 0);
    }
    for (int i = 0; i < 2; ++i)
      for (int j = 0; j < 2; ++j)
        for (int r = 0; r < 4; ++r) {
          int e = i * 16 + qd * 4 + r;
          int col = nb * 128 + w * 32 + j * 16 + ln;
          Wvt[(size_t)(h * 32 + e) * 2048 + col] = __float2bfloat16(acc[i][j][r]);
        }
  } else if (blk < 512) {
    // fold_ow: W~ot[d_out][(h*32+e)]
    int rem = blk - 256;
    int mb = rem & 15, h = rem >> 4;
    f32x4 acc[2][2] = {};
    for (int kt = 0; kt < 4; ++kt) {
      bf16x8 af[2], bfr[2];
      for (int i = 0; i < 2; ++i)
        af[i] = *(const bf16x8*)&WtO[(size_t)(mb * 128 + w * 32 + i * 16 + ln) * 2048 +
                                     h * 128 + kt * 32 + qd * 8];
      for (int j = 0; j < 2; ++j)
        bfr[j] = *(const bf16x8*)&small[SM_WD + (j * 16 + ln) * 128 + kt * 32 + qd * 8];
      for (int i = 0; i < 2; ++i)
        for (int j = 0; j < 2; ++j)
          acc[i][j] = __builtin_amdgcn_mfma_f32_16x16x32_bf16(af[i], bfr[j], acc[i][j], 0, 0, 0);
    }
    for (int i = 0; i < 2; ++i)
      for (int j = 0; j < 2; ++j)
        for (int r = 0; r < 4; ++r) {
          int row = mb * 128 + w * 32 + i * 16 + qd * 4 + r;
          int col = h * 32 + j * 16 + ln;
          Wot[(size_t)row * 512 + col] = __float2bfloat16(acc[i][j][r]);
        }
  } else {
    // fold_bias_final
    int f32 = *flagp;
    int tid = (blk - 512) * 256 + t;  // 0..2559
    if (tid < 2048) {
      float s = cv1(boS, tid, f32);
      for (int kb = 0; kb < 16; ++kb) s += bo_part[kb * 2048 + tid];
      boF[tid] = s;
    } else if (tid < 2560) {
      int j = tid - 2048, h = j >> 5, e = j & 31;
      float s = cv1(bvcS, e, f32);
      for (int hd = 0; hd < 128; ++hd)
        s += cv1(bvS, h * 128 + hd, f32) * cv1(WvcS, (size_t)hd * 32 + e, f32);
      bvF[j] = s;
    }
  }
}

// ---------------- QK GEMM + fused RoPE + compression; XCD-swizzled grid ----------------
#define ESTR 136
__global__ __launch_bounds__(256) void gemm_qk_compress(
    const bf16* __restrict__ A, const bf16* __restrict__ Bt,
    const bf16* __restrict__ small, const bf16* __restrict__ wctG,
    bf16* __restrict__ qc, bf16* __restrict__ kc) {
  __shared__ bf16 sh[128 * ESTR];  // 34816 B; first 16KB doubles as lA|lB
  bf16* lA = sh;
  bf16* lB = sh + 4096;
  const int K = 2048;
  // XCD-bijective swizzle: nwg=1024, 8 XCDs. XCD x gets bm in [4x,4x+4), bn-fastest.
  int id = blockIdx.x;
  int lg = (id & 7) * 128 + (id >> 3);
  int bm = lg >> 5, bn = lg & 31;
  int reg = bn >> 4, h = bn & 15;
  int t = threadIdx.x;
  int lane = t & 63, w = t >> 6;
  int wm = (w >> 1) * 64, wn = (w & 1) * 64;
  int qd = lane >> 4, ln = lane & 15;

  f32x4 acc[4][4] = {};
  const bf16* Ab = A + (size_t)(bm * 128) * K;
  const bf16* Bb = Bt + (size_t)(bn * 128) * K;

  for (int kt = 0; kt < K; kt += 32) {
    for (int p = 0; p < 2; ++p) {
      int slot = t + p * 256;
      int r = slot >> 2, c = (slot & 3) * 8;
      GLDS16(&Ab[(size_t)r * K + kt + c], &lA[slot * 8]);
      GLDS16(&Bb[(size_t)r * K + kt + c], &lB[slot * 8]);
    }
    __syncthreads();
    bf16x8 af[4], bfr[4];
    for (int i = 0; i < 4; ++i) af[i] = *(bf16x8*)&lA[(wm + i * 16 + ln) * 32 + qd * 8];
    for (int j = 0; j < 4; ++j) bfr[j] = *(bf16x8*)&lB[(wn + j * 16 + ln) * 32 + qd * 8];
    for (int i = 0; i < 4; ++i)
      for (int j = 0; j < 4; ++j)
        acc[i][j] = __builtin_amdgcn_mfma_f32_16x16x32_bf16(af[i], bfr[j], acc[i][j], 0, 0, 0);
    __syncthreads();
  }

  // epilogue 1: acc + bias -> LDS tile (row = block-local l, col = head dim)
  for (int j = 0; j < 4; ++j) {
    int col = wn + j * 16 + ln;
    float bv = __bfloat162float(small[SM_BQKV + bn * 128 + col]);
    for (int i = 0; i < 4; ++i)
      for (int r = 0; r < 4; ++r)
        sh[(wm + i * 16 + qd * 4 + r) * ESTR + col] = __float2bfloat16(acc[i][j][r] + bv);
  }
  __syncthreads();

  // epilogue 2: RoPE + compress 32 l-rows per wave
  int r0 = w * 32;
  int b = bm >> 4;
  int bh = b * Hn + h;
  bf16x8 bfr2[2][4];
  for (int nt = 0; nt < 2; ++nt)
    for (int kt = 0; kt < 4; ++kt)
      bfr2[nt][kt] = *(const bf16x8*)&wctG[reg * 4096 + (nt * 16 + ln) * 128 + kt * 32 + qd * 8];
  float bc[2];
  bc[0] = __bfloat162float(small[SM_BC + reg * 32 + ln]);
  bc[1] = __bfloat162float(small[SM_BC + reg * 32 + 16 + ln]);

  for (int mt = 0; mt < 2; ++mt) {
    int lb = r0 + mt * 16 + ln;
    int lg2 = (bm & 15) * 128 + lb;
    f32x4 c2[2] = {};
    for (int kt = 0; kt < 4; ++kt) {
      uint4 u = *(uint4*)&sh[lb * ESTR + kt * 32 + qd * 8];
      bf16* e8 = (bf16*)&u;
      int pbase = kt * 16 + qd * 4;
      for (int j = 0; j < 4; ++j) {
        float cvv = __bfloat162float(small[SM_COS + (size_t)lg2 * 64 + pbase + j]);
        float svv = __bfloat162float(small[SM_SIN + (size_t)lg2 * 64 + pbase + j]);
        float ev = __bfloat162float(e8[2 * j]);
        float ov = __bfloat162float(e8[2 * j + 1]);
        e8[2 * j] = __float2bfloat16(ev * cvv - ov * svv);
        e8[2 * j + 1] = __float2bfloat16(ev * svv + ov * cvv);
      }
      bf16x8 a = *(bf16x8*)&u;
      c2[0] = __builtin_amdgcn_mfma_f32_16x16x32_bf16(a, bfr2[0][kt], c2[0], 0, 0, 0);
      c2[1] = __builtin_amdgcn_mfma_f32_16x16x32_bf16(a, bfr2[1][kt], c2[1], 0, 0, 0);
    }
    int lgbase = (bm & 15) * 128 + r0 + mt * 16 + qd * 4;
    bf16* dst = (reg == 0) ? qc : kc;
    for (int nt = 0; nt < 2; ++nt)
      for (int r = 0; r < 4; ++r)
        dst[((size_t)bh * Lseq + lgbase + r) * 32 + nt * 16 + ln] =
            __float2bfloat16(c2[nt][r] + bc[nt]);
  }
}

// ---------------- V-fold GEMM: vcT[(b*512+n)][l] = x @ W~vt^T + bvF ----------------
__global__ __launch_bounds__(256) void gemm_v_fold(const bf16* __restrict__ A,
                                                   const bf16* __restrict__ Wvt,
                                                   const float* __restrict__ bvF,
                                                   bf16* __restrict__ vcT) {
  __shared__ bf16 lA[64 * 32];
  __shared__ bf16 lB[64 * 32];
  const int K = 2048;
  int bm = blockIdx.y, nb = blockIdx.x;
  int t = threadIdx.x;
  int lane = t & 63, w = t >> 6;
  int wm = (w >> 1) * 32, wn = (w & 1) * 32;
  int qd = lane >> 4, ln = lane & 15;

  f32x4 acc[2][2] = {};
  const bf16* Ab = A + (size_t)(bm * 64) * K;
  const bf16* Bb = Wvt + (size_t)(nb * 64) * K;

  int r = t >> 2, c = (t & 3) * 8;
  for (int kt = 0; kt < K; kt += 32) {
    GLDS16(&Ab[(size_t)r * K + kt + c], &lA[t * 8]);
    GLDS16(&Bb[(size_t)r * K + kt + c], &lB[t * 8]);
    __syncthreads();
    bf16x8 af[2], bfr[2];
    for (int i = 0; i < 2; ++i) af[i] = *(bf16x8*)&lA[(wm + i * 16 + ln) * 32 + qd * 8];
    for (int j = 0; j < 2; ++j) bfr[j] = *(bf16x8*)&lB[(wn + j * 16 + ln) * 32 + qd * 8];
    for (int i = 0; i < 2; ++i)
      for (int j = 0; j < 2; ++j)
        acc[i][j] = __builtin_amdgcn_mfma_f32_16x16x32_bf16(af[i], bfr[j], acc[i][j], 0, 0, 0);
    __syncthreads();
  }

  int b = bm >> 5;
  for (int j = 0; j < 2; ++j) {
    int n = nb * 64 + wn + j * 16 + ln;
    float bb = bvF[n];
    for (int i = 0; i < 2; ++i) {
      int lloc = (bm & 31) * 64 + wm + i * 16 + qd * 4;
      bf16 p4[4] __attribute__((aligned(8)));
      for (int rr = 0; rr < 4; ++rr) p4[rr] = __float2bfloat16(acc[i][j][rr] + bb);
      *(uint2*)&vcT[((size_t)(b * 512 + n)) * 2048 + lloc] = *(uint2*)p4;
    }
  }
}

// ---------------- output GEMM: d_out = attn @ Wot^T + boF (fp32 bias), K=512 ----------------
__global__ __launch_bounds__(256) void gemm_bias_out(const bf16* __restrict__ A,
                                                     const bf16* __restrict__ Bt,
                                                     const float* __restrict__ bias,
                                                     void* __restrict__ C,
                                                     int M, int N, int K,
                                                     const int* __restrict__ flagp) {
  __shared__ bf16 lA[128 * 32];
  __shared__ bf16 lB[128 * 32];
  int f32out = *flagp;
  int bm = blockIdx.y, bn = blockIdx.x;
  int t = threadIdx.x;
  int lane = t & 63, w = t >> 6;
  int wm = (w >> 1) * 64, wn = (w & 1) * 64;
  int qd = lane >> 4, ln = lane & 15;

  f32x4 acc[4][4] = {};
  const bf16* Ab = A + (size_t)(bm * 128) * K;
  const bf16* Bb = Bt + (size_t)(bn * 128) * K;

  for (int kt = 0; kt < K; kt += 32) {
    for (int p = 0; p < 2; ++p) {
      int slot = t + p * 256;
      int r = slot >> 2, c = (slot & 3) * 8;
      GLDS16(&Ab[(size_t)r * K + kt + c], &lA[slot * 8]);
      GLDS16(&Bb[(size_t)r * K + kt + c], &lB[slot * 8]);
    }
    __syncthreads();
    bf16x8 af[4], bfr[4];
    for (int i = 0; i < 4; ++i) af[i] = *(bf16x8*)&lA[(wm + i * 16 + ln) * 32 + qd * 8];
    for (int j = 0; j < 4; ++j) bfr[j] = *(bf16x8*)&lB[(wn + j * 16 + ln) * 32 + qd * 8];
    for (int i = 0; i < 4; ++i)
      for (int j = 0; j < 4; ++j)
        acc[i][j] = __builtin_amdgcn_mfma_f32_16x16x32_bf16(af[i], bfr[j], acc[i][j], 0, 0, 0);
    __syncthreads();
  }
  for (int i = 0; i < 4; ++i)
    for (int j = 0; j < 4; ++j) {
      int col = bn * 128 + wn + j * 16 + ln;
      float bv = bias[col];
      for (int r = 0; r < 4; ++r) {
        int row = bm * 128 + wm + i * 16 + qd * 4 + r;
        float v = acc[i][j][r] + bv;
        if (f32out) ((float*)C)[(size_t)row * N + col] = v;
        else ((bf16*)C)[(size_t)row * N + col] = __float2bfloat16(v);
      }
    }
}

// ---------------- flash attention R9: 64-key chunks, 4-wave KV split + merge ----------------
__global__ __launch_bounds__(256) void flash32(const bf16* __restrict__ qc,
                                               const bf16* __restrict__ kc,
                                               const bf16* __restrict__ vcT,
                                               bf16* __restrict__ attn) {
  __shared__ bf16 pbuf[4][16 * 72];     // 9216 B
  __shared__ float oL[4][16][33];       // 8448 B
  __shared__ float mL[4][16];
  __shared__ float lsL[4][16];
  int t = threadIdx.x;
  int lane = t & 63, w = t >> 6;
  int qd = lane >> 4, ln = lane & 15;
  int blk = blockIdx.x;                 // grid 4096 = 32 bh x 128 q-tiles
  int j = blk & 127;
  int bh = blk >> 7, h = bh & 15, b = bh >> 4;
  int q0 = j * 16;

  bf16x8 qf = *(const bf16x8*)&qc[((size_t)bh * Lseq + q0 + ln) * 32 + qd * 8];

  f32x4 o0 = {}, o1 = {};
  float m[4], ls[4];
  for (int r = 0; r < 4; ++r) { m[r] = -1e30f; ls[r] = 0.f; }
  const float scale = 0.17677669529663687f;  // 1/sqrt(32)

  int n64 = (q0 + 16 + 63) >> 6;        // causal KV chunks of 64
  int nw = (n64 + 3) >> 2;
  int c0 = w * nw;
  int c1 = min(c0 + nw, n64);

  bf16* pb = pbuf[w];
  for (int ci = c0; ci < c1; ++ci) {
    int k0 = ci * 64;
    f32x4 s[4];
    for (int c = 0; c < 4; ++c) {
      bf16x8 kf = *(const bf16x8*)&kc[((size_t)bh * Lseq + k0 + c * 16 + ln) * 32 + qd * 8];
      f32x4 z = {};
      s[c] = __builtin_amdgcn_mfma_f32_16x16x32_bf16(qf, kf, z, 0, 0, 0);
    }
    float sv[4][4], alpha[4];
    for (int r = 0; r < 4; ++r) {
      int qrow = q0 + qd * 4 + r;
      for (int c = 0; c < 4; ++c)
        sv[c][r] = (k0 + c * 16 + ln <= qrow) ? s[c][r] * scale : -1e30f;
    }
    for (int r = 0; r < 4; ++r) {
      float mx = fmaxf(fmaxf(sv[0][r], sv[1][r]), fmaxf(sv[2][r], sv[3][r]));
      for (int off = 1; off < 16; off <<= 1) mx = fmaxf(mx, __shfl_xor(mx, off, 64));
      float mn = fmaxf(m[r], mx);
      alpha[r] = __expf(m[r] - mn);
      m[r] = mn;
      float rs = 0.f;
      for (int c = 0; c < 4; ++c) { sv[c][r] = __expf(sv[c][r] - mn); rs += sv[c][r]; }
      ls[r] = ls[r] * alpha[r] + rs;
      o0[r] *= alpha[r];
      o1[r] *= alpha[r];
    }
    for (int r = 0; r < 4; ++r)
      for (int c = 0; c < 4; ++c)
        pb[(qd * 4 + r) * 72 + c * 16 + ln] = __float2bfloat16(sv[c][r]);
    asm volatile("s_waitcnt lgkmcnt(0)" ::: "memory");
    bf16x8 pf0 = *(bf16x8*)&pb[ln * 72 + qd * 8];
    bf16x8 pf1 = *(bf16x8*)&pb[ln * 72 + 32 + qd * 8];
    bf16x8 vf00 = *(const bf16x8*)&vcT[((size_t)bh * 32 + ln) * Lseq + k0 + qd * 8];
    bf16x8 vf01 = *(const bf16x8*)&vcT[((size_t)bh * 32 + ln) * Lseq + k0 + 32 + qd * 8];
    bf16x8 vf10 = *(const bf16x8*)&vcT[((size_t)bh * 32 + 16 + ln) * Lseq + k0 + qd * 8];
    bf16x8 vf11 = *(const bf16x8*)&vcT[((size_t)bh * 32 + 16 + ln) * Lseq + k0 + 32 + qd * 8];
    o0 = __builtin_amdgcn_mfma_f32_16x16x32_bf16(pf0, vf00, o0, 0, 0, 0);
    o0 = __builtin_amdgcn_mfma_f32_16x16x32_bf16(pf1, vf01, o0, 0, 0, 0);
    o1 = __builtin_amdgcn_mfma_f32_16x16x32_bf16(pf0, vf10, o1, 0, 0, 0);
    o1 = __builtin_amdgcn_mfma_f32_16x16x32_bf16(pf1, vf11, o1, 0, 0, 0);
  }

  // one end reduce of the per-lane lsum partials
  for (int r = 0; r < 4; ++r)
    for (int off = 1; off < 16; off <<= 1) ls[r] += __shfl_xor(ls[r], off, 64);

  // write wave partials
  for (int r = 0; r < 4; ++r) {
    int row = qd * 4 + r;
    oL[w][row][ln] = o0[r];
    oL[w][row][16 + ln] = o1[r];
    if (ln == 0) { mL[w][row] = m[r]; lsL[w][row] = ls[r]; }
  }
  __syncthreads();

  // merge 4 wave-partials (flash-decode combine)
  for (int idx = t; idx < 512; idx += 256) {
    int row = idx >> 5, col = idx & 31;
    float m0 = mL[0][row], m1 = mL[1][row], m2 = mL[2][row], m3 = mL[3][row];
    float ms = fmaxf(fmaxf(m0, m1), fmaxf(m2, m3));
    float e0 = __expf(m0 - ms), e1 = __expf(m1 - ms);
    float e2 = __expf(m2 - ms), e3 = __expf(m3 - ms);
    float lsum = lsL[0][row] * e0 + lsL[1][row] * e1 + lsL[2][row] * e2 + lsL[3][row] * e3;
    float val = oL[0][row][col] * e0 + oL[1][row][col] * e1 +
                oL[2][row][col] * e2 + oL[3][row][col] * e3;
    int l = q0 + row;
    attn[((size_t)(b * Lseq + l)) * 512 + h * 32 + col] = __float2bfloat16(val / lsum);
  }
}

extern "C" void kernel_launch(void* const* d_in, const int* in_sizes, int n_in,
                              void* d_out, int out_size, void* d_ws, size_t ws_size,
                              hipStream_t stream) {
  const void* x = d_in[0];
  const void* cosS = d_in[1];
  const void* sinS = d_in[2];
  const void* Wq = d_in[3];
  const void* bq = d_in[4];
  const void* Wk = d_in[5];
  const void* bk = d_in[6];
  const void* Wv = d_in[7];
  const void* bv = d_in[8];
  const void* Wqc = d_in[9];
  const void* bqc = d_in[10];
  const void* Wkc = d_in[11];
  const void* bkc = d_in[12];
  const void* Wvc = d_in[13];
  const void* bvc = d_in[14];
  const void* Wd = d_in[15];
  const void* bd = d_in[16];
  const void* Wo = d_in[17];
  const void* bo = d_in[18];

  char* ws = (char*)d_ws;
  size_t off = 0;
  auto alloc = [&](size_t bytes) {
    char* p = ws + off;
    off += (bytes + 255) & ~(size_t)255;
    return p;
  };
  int* flag = (int*)alloc(256);
  bf16* small = (bf16*)alloc((size_t)SM_TOT * 2);
  bf16* wctG = (bf16*)alloc((size_t)12288 * 2);
  bf16* wdtG = (bf16*)alloc((size_t)4096 * 2);
  bf16* xb = (bf16*)alloc((size_t)4096 * 2048 * 2);
  bf16* WvB = (bf16*)alloc((size_t)2048 * 2048 * 2);
  bf16* WtQK = (bf16*)alloc((size_t)4096 * 2048 * 2);
  bf16* WtO = (bf16*)alloc((size_t)2048 * 2048 * 2);
  bf16* Wvt = (bf16*)alloc((size_t)512 * 2048 * 2);
  bf16* Wot = (bf16*)alloc((size_t)2048 * 512 * 2);
  float* bo_part = (float*)alloc((size_t)16 * 2048 * 4);
  float* boF = (float*)alloc((size_t)2048 * 4);
  float* bvF = (float*)alloc((size_t)512 * 4);
  bf16* qcW = (bf16*)alloc((size_t)65536 * 32 * 2);
  bf16* kcW = (bf16*)alloc((size_t)65536 * 32 * 2);
  bf16* vcTW = (bf16*)alloc((size_t)65536 * 32 * 2);
  bf16* attnW = (bf16*)alloc((size_t)4096 * 512 * 2);

  dim3 tb(256);
  detect_dtype<<<1, 64, 0, stream>>>((const ushort*)x, flag);
  prep_all<<<NB_PREP_ALL, tb, 0, stream>>>(
      x, cosS, sinS, Wq, Wk, Wv, Wo, Wqc, Wkc, Wvc, bqc, bkc, bvc, Wd, bd, bo,
      bq, bk, bv, xb, WvB, WtQK, WtO, small, wctG, wdtG, bo_part, flag);
  fold_all<<<522, tb, 0, stream>>>(WvB, wctG, WtO, small, bo, bo_part, bv, bvc,
                                   Wvc, Wvt, Wot, boF, bvF, flag);
  gemm_qk_compress<<<1024, tb, 0, stream>>>(xb, WtQK, small, wctG, qcW, kcW);
  gemm_v_fold<<<dim3(8, 64), tb, 0, stream>>>(xb, Wvt, bvF, vcTW);
  flash32<<<4096, tb, 0, stream>>>(qcW, kcW, vcTW, attnW);
  gemm_bias_out<<<dim3(16, 32), tb, 0, stream>>>(attnW, Wot, boF, d_out, 4096, 2048,
                                                 512, flag);
}

// Round 6
// 394.181 us; speedup vs baseline: 1.8768x; 1.0378x over previous
//
#include <hip/hip_runtime.h>
#include <hip/hip_bf16.h>

// CausalMLA: B=2, L=2048, D=2048, H=16, HD=128, LD=32. Inputs fp32 or bf16
// (runtime-detected); pipeline bf16/MFMA; output dtype follows input.
// R5: algebraic folds — V compress folded into weights, decompress into Wo.
// R6: fold_bias parallelized. R7: lean split QK / V-fold GEMMs.
// R8: flash32 1 q-tile/block, 4-wave KV split + flash-decode merge.
// R9: prep fused (13->7 dispatches); flash 64-key chunks.
// R10: (a) XCD swizzle reverted (FETCH 85->140MB regression). (b) v_fold
//     merged into qk dispatch as disjoint block branch (tail overlap).
//     (c) flash32: V(ci)/K(ci+1) loads issued BEFORE softmax chain (were
//     serialized behind the lgkmcnt memory-clobber); exp2-domain softmax.
//     (d) qk epilogue cos/sin vectorized (uint2).

#define Bsz 2
#define Lseq 2048
#define Dmod 2048
#define Hn 16
#define HDim 128
#define LDim 32

typedef __bf16 bf16x8 __attribute__((ext_vector_type(8)));
typedef float f32x4 __attribute__((ext_vector_type(4)));
typedef __hip_bfloat16 bf16;

#define GLDS16(g, l)                                                    \
  __builtin_amdgcn_global_load_lds(                                     \
      (const __attribute__((address_space(1))) unsigned int*)(g),       \
      (__attribute__((address_space(3))) unsigned int*)(l), 16, 0, 0)

// ---- small-constants area layout (bf16 element offsets inside `small`) ----
#define SM_COS 0
#define SM_SIN 131072
#define SM_WC 262144     // Wqc|Wkc|Wvc 3*4096
#define SM_BC 274432     // bqc|bkc|bvc 3*32
#define SM_WD 274528     // 4096 (row-major Wd[e][hd] — used by fold_ow)
#define SM_BD 278624     // 128
#define SM_BO 278752     // 2048
#define SM_BQKV 280800   // bq|bk|bv 3*2048
#define SM_TOT 286944

// ---------------- dtype detector ----------------
__global__ void detect_dtype(const ushort* __restrict__ x, int* __restrict__ flag) {
  int t = threadIdx.x;  // 64 threads
  int bad = 0;
  for (int k = 0; k < 4; ++k) {
    ushort u = x[t * 4 + k];
    int ex = (u >> 7) & 0xFF;
    if (ex >= 0xC0) bad = 1;
  }
  unsigned long long b = __ballot(bad);
  if (t == 0) *flag = (b != 0ULL) ? 1 : 0;  // 1 = inputs are fp32
}

__device__ inline void conv8(const void* src, size_t so, bf16* dst, size_t dof, int f32) {
  if (f32) {
    const float* s = (const float*)src + so;
    bf16 tmp[8] __attribute__((aligned(16)));
    for (int j = 0; j < 8; ++j) tmp[j] = __float2bfloat16(s[j]);
    *(uint4*)&dst[dof] = *(uint4*)tmp;
  } else {
    *(uint4*)&dst[dof] = *(const uint4*)((const ushort*)src + so);
  }
}

__device__ inline float cv1(const void* s, size_t i, int f32) {
  return f32 ? ((const float*)s)[i] : __bfloat162float(((const bf16*)s)[i]);
}

// ---------------- prep_all: transpose3 | conv Wv | conv x | small-prep | fbp ----------------
#define NB_T3 3072
#define NB_WV 2048
#define NB_CX 4096
#define NB_PREP 160
#define NB_FBP 256
#define NB_PREP_ALL (NB_T3 + NB_WV + NB_CX + NB_PREP + NB_FBP)  // 9632

__global__ __launch_bounds__(256) void prep_all(
    const void* xS, const void* cosS, const void* sinS, const void* WqS,
    const void* WkS, const void* WvS, const void* WoS, const void* WqcS,
    const void* WkcS, const void* WvcS, const void* bqcS, const void* bkcS,
    const void* bvcS, const void* WdS, const void* bdS, const void* boS,
    const void* bqS, const void* bkS, const void* bvS,
    bf16* __restrict__ xb, bf16* __restrict__ WvB, bf16* __restrict__ WtQK,
    bf16* __restrict__ WtO, bf16* __restrict__ small, bf16* __restrict__ wctG,
    bf16* __restrict__ wdtG, float* __restrict__ bo_part,
    const int* __restrict__ flagp) {
  __shared__ __align__(16) char shm[16640];
  int f32 = *flagp;
  int blk = blockIdx.x;
  int t = threadIdx.x;

  if (blk < NB_T3) {
    // --- weight transpose (Wq, Wk, Wo) ---
    float (*tile)[65] = (float(*)[65])shm;
    int z = blk >> 10, rem = blk & 1023;
    const void* W = (z == 0) ? WqS : (z == 1) ? WkS : WoS;
    bf16* Wt = (z == 2) ? WtO : (WtQK + (size_t)z * 2048 * 2048);
    int n0 = (rem & 31) * 64, k0 = (rem >> 5) * 64;
    int x = (t & 7) * 8, y = t >> 3;
    for (int p = 0; p < 2; ++p) {
      int r = y + p * 32;
      if (f32) {
        const float* src = (const float*)W + (size_t)(k0 + r) * 2048 + n0 + x;
        float4 a = *(const float4*)src;
        float4 b2 = *(const float4*)(src + 4);
        tile[r][x + 0] = a.x; tile[r][x + 1] = a.y; tile[r][x + 2] = a.z; tile[r][x + 3] = a.w;
        tile[r][x + 4] = b2.x; tile[r][x + 5] = b2.y; tile[r][x + 6] = b2.z; tile[r][x + 7] = b2.w;
      } else {
        const ushort* src = (const ushort*)W + (size_t)(k0 + r) * 2048 + n0 + x;
        uint4 u = *(const uint4*)src;
        bf16* e = (bf16*)&u;
        for (int jj = 0; jj < 8; ++jj) tile[r][x + jj] = __bfloat162float(e[jj]);
      }
    }
    __syncthreads();
    for (int p = 0; p < 2; ++p) {
      int n = y + p * 32;
      bf16 tmp[8] __attribute__((aligned(16)));
      for (int jj = 0; jj < 8; ++jj) tmp[jj] = __float2bfloat16(tile[x + jj][n]);
      *(uint4*)&Wt[(size_t)(n0 + n) * 2048 + k0 + x] = *(uint4*)tmp;
    }
  } else if (blk < NB_T3 + NB_WV) {
    // --- Wv -> bf16 copy ---
    size_t e = ((size_t)(blk - NB_T3) * 256 + t) * 8;
    conv8(WvS, e, WvB, e, f32);
  } else if (blk < NB_T3 + NB_WV + NB_CX) {
    // --- x -> bf16 copy ---
    size_t e = ((size_t)(blk - NB_T3 - NB_WV) * 256 + t) * 8;
    conv8(xS, e, xb, e, f32);
  } else if (blk < NB_T3 + NB_WV + NB_CX + NB_PREP) {
    // --- small-area + wctG/wdtG prep ---
    int tid = (blk - NB_T3 - NB_WV - NB_CX) * 256 + t;  // 0..40959
    if (tid < SM_TOT / 8) {
      size_t e = (size_t)tid * 8;
      const void* src;
      size_t so;
      if (e < SM_SIN) { src = cosS; so = e - SM_COS; }
      else if (e < SM_WC) { src = sinS; so = e - SM_SIN; }
      else if (e < SM_BC) { size_t r = e - SM_WC; src = (r < 4096) ? WqcS : (r < 8192) ? WkcS : WvcS; so = r & 4095; }
      else if (e < SM_WD) { size_t r = e - SM_BC; src = (r < 32) ? bqcS : (r < 64) ? bkcS : bvcS; so = r & 31; }
      else if (e < SM_BD) { src = WdS; so = e - SM_WD; }
      else if (e < SM_BO) { src = bdS; so = e - SM_BD; }
      else if (e < SM_BQKV) { src = boS; so = e - SM_BO; }
      else { size_t r = e - SM_BQKV; src = (r < 2048) ? bqS : (r < 4096) ? bkS : bvS; so = r & 2047; }
      conv8(src, so, small, e, f32);
    } else {
      int idx = tid - SM_TOT / 8;
      for (int i = idx; i < 16384; i += 40960 - SM_TOT / 8) {
        if (i < 12288) {
          int reg = i >> 12, rem2 = i & 4095, n = rem2 >> 7, k = rem2 & 127;
          const void* src = (reg == 0) ? WqcS : (reg == 1) ? WkcS : WvcS;
          wctG[i] = __float2bfloat16(cv1(src, (size_t)k * 32 + n, f32));
        } else {
          int i2 = i - 12288, o = i2 >> 5, e = i2 & 31;
          wdtG[i2] = __float2bfloat16(cv1(WdS, (size_t)e * 128 + o, f32));
        }
      }
    }
  } else {
    // --- fold_bias partial: bo_part[kb][col] ---
    float* red = (float*)shm;
    int rem = blk - (NB_T3 + NB_WV + NB_CX + NB_PREP);
    int nb = rem & 15, kb = rem >> 4;
    int col = nb * 128 + (t & 127);
    int half = t >> 7;
    float s = 0.f;
    int kbase = kb * 128 + half * 64;
    for (int i = 0; i < 64; ++i) {
      int k = kbase + i;
      s += cv1(bdS, k & 127, f32) * cv1(WoS, (size_t)k * 2048 + col, f32);
    }
    red[t] = s;
    __syncthreads();
    if (half == 0) bo_part[kb * 2048 + col] = red[t] + red[t + 128];
  }
}

// ---------------- fold_all: fold_vw | fold_ow | fold_bias_final ----------------
__global__ __launch_bounds__(256) void fold_all(
    const bf16* __restrict__ WvB, const bf16* __restrict__ wctG,
    const bf16* __restrict__ WtO, const bf16* __restrict__ small,
    const void* boS, const float* __restrict__ bo_part, const void* bvS,
    const void* bvcS, const void* WvcS, bf16* __restrict__ Wvt,
    bf16* __restrict__ Wot, float* __restrict__ boF, float* __restrict__ bvF,
    const int* __restrict__ flagp) {
  int blk = blockIdx.x;
  int t = threadIdx.x, lane = t & 63, w = t >> 6;
  int qd = lane >> 4, ln = lane & 15;
  if (blk < 256) {
    // fold_vw: W~vt[(h*32+e)][d_in]
    int nb = blk & 15, h = blk >> 4;
    f32x4 acc[2][2] = {};
    for (int kt = 0; kt < 4; ++kt) {
      bf16x8 af[2], bfr[2];
      for (int i = 0; i < 2; ++i)
        af[i] = *(const bf16x8*)&wctG[8192 + (i * 16 + ln) * 128 + kt * 32 + qd * 8];
      for (int j = 0; j < 2; ++j)
        bfr[j] = *(const bf16x8*)&WvB[(size_t)(nb * 128 + w * 32 + j * 16 + ln) * 2048 +
                                      h * 128 + kt * 32 + qd * 8];
      for (int i = 0; i < 2; ++i)
        for (int j = 0; j < 2; ++j)
          acc[i][j] = __builtin_amdgcn_mfma_f32_16x16x32_bf16(af[i], bfr[j], acc[i][j], 0, 0, 0);
    }
    for (int i = 0; i < 2; ++i)
      for (int j = 0; j < 2; ++j)
        for (int r = 0; r < 4; ++r) {
          int e = i * 16 + qd * 4 + r;
          int col = nb * 128 + w * 32 + j * 16 + ln;
          Wvt[(size_t)(h * 32 + e) * 2048 + col] = __float2bfloat16(acc[i][j][r]);
        }
  } else if (blk < 512) {
    // fold_ow: W~ot[d_out][(h*32+e)]
    int rem = blk - 256;
    int mb = rem & 15, h = rem >> 4;
    f32x4 acc[2][2] = {};
    for (int kt = 0; kt < 4; ++kt) {
      bf16x8 af[2], bfr[2];
      for (int i = 0; i < 2; ++i)
        af[i] = *(const bf16x8*)&WtO[(size_t)(mb * 128 + w * 32 + i * 16 + ln) * 2048 +
                                     h * 128 + kt * 32 + qd * 8];
      for (int j = 0; j < 2; ++j)
        bfr[j] = *(const bf16x8*)&small[SM_WD + (j * 16 + ln) * 128 + kt * 32 + qd * 8];
      for (int i = 0; i < 2; ++i)
        for (int j = 0; j < 2; ++j)
          acc[i][j] = __builtin_amdgcn_mfma_f32_16x16x32_bf16(af[i], bfr[j], acc[i][j], 0, 0, 0);
    }
    for (int i = 0; i < 2; ++i)
      for (int j = 0; j < 2; ++j)
        for (int r = 0; r < 4; ++r) {
          int row = mb * 128 + w * 32 + i * 16 + qd * 4 + r;
          int col = h * 32 + j * 16 + ln;
          Wot[(size_t)row * 512 + col] = __float2bfloat16(acc[i][j][r]);
        }
  } else {
    // fold_bias_final
    int f32 = *flagp;
    int tid = (blk - 512) * 256 + t;  // 0..2559
    if (tid < 2048) {
      float s = cv1(boS, tid, f32);
      for (int kb = 0; kb < 16; ++kb) s += bo_part[kb * 2048 + tid];
      boF[tid] = s;
    } else if (tid < 2560) {
      int j = tid - 2048, h = j >> 5, e = j & 31;
      float s = cv1(bvcS, e, f32);
      for (int hd = 0; hd < 128; ++hd)
        s += cv1(bvS, h * 128 + hd, f32) * cv1(WvcS, (size_t)hd * 32 + e, f32);
      bvF[j] = s;
    }
  }
}

// ---------------- merged QKV: blocks 0..1023 = QK+RoPE+compress; 1024..1535 = V-fold ----------------
#define ESTR 136
__global__ __launch_bounds__(256) void gemm_qkv(
    const bf16* __restrict__ A, const bf16* __restrict__ Bt,
    const bf16* __restrict__ Wvt, const bf16* __restrict__ small,
    const bf16* __restrict__ wctG, const float* __restrict__ bvF,
    bf16* __restrict__ qc, bf16* __restrict__ kc, bf16* __restrict__ vcT) {
  __shared__ bf16 sh[128 * ESTR];  // 34816 B; first 16KB doubles as lA|lB
  const int K = 2048;
  int id = blockIdx.x;
  int t = threadIdx.x;
  int lane = t & 63, w = t >> 6;
  int qd = lane >> 4, ln = lane & 15;

  if (id < 1024) {
    // ---- QK path (R8-proven): bn fastest ----
    bf16* lA = sh;
    bf16* lB = sh + 4096;
    int bn = id & 31, bm = id >> 5;
    int reg = bn >> 4, h = bn & 15;
    int wm = (w >> 1) * 64, wn = (w & 1) * 64;

    f32x4 acc[4][4] = {};
    const bf16* Ab = A + (size_t)(bm * 128) * K;
    const bf16* Bb = Bt + (size_t)(bn * 128) * K;

    for (int kt = 0; kt < K; kt += 32) {
      for (int p = 0; p < 2; ++p) {
        int slot = t + p * 256;
        int r = slot >> 2, c = (slot & 3) * 8;
        GLDS16(&Ab[(size_t)r * K + kt + c], &lA[slot * 8]);
        GLDS16(&Bb[(size_t)r * K + kt + c], &lB[slot * 8]);
      }
      __syncthreads();
      bf16x8 af[4], bfr[4];
      for (int i = 0; i < 4; ++i) af[i] = *(bf16x8*)&lA[(wm + i * 16 + ln) * 32 + qd * 8];
      for (int j = 0; j < 4; ++j) bfr[j] = *(bf16x8*)&lB[(wn + j * 16 + ln) * 32 + qd * 8];
      for (int i = 0; i < 4; ++i)
        for (int j = 0; j < 4; ++j)
          acc[i][j] = __builtin_amdgcn_mfma_f32_16x16x32_bf16(af[i], bfr[j], acc[i][j], 0, 0, 0);
      __syncthreads();
    }

    // epilogue 1: acc + bias -> LDS tile
    for (int j = 0; j < 4; ++j) {
      int col = wn + j * 16 + ln;
      float bv = __bfloat162float(small[SM_BQKV + bn * 128 + col]);
      for (int i = 0; i < 4; ++i)
        for (int r = 0; r < 4; ++r)
          sh[(wm + i * 16 + qd * 4 + r) * ESTR + col] = __float2bfloat16(acc[i][j][r] + bv);
    }
    __syncthreads();

    // epilogue 2: RoPE + compress 32 l-rows per wave
    int r0 = w * 32;
    int b = bm >> 4;
    int bh = b * Hn + h;
    bf16x8 bfr2[2][4];
    for (int nt = 0; nt < 2; ++nt)
      for (int kt = 0; kt < 4; ++kt)
        bfr2[nt][kt] = *(const bf16x8*)&wctG[reg * 4096 + (nt * 16 + ln) * 128 + kt * 32 + qd * 8];
    float bc[2];
    bc[0] = __bfloat162float(small[SM_BC + reg * 32 + ln]);
    bc[1] = __bfloat162float(small[SM_BC + reg * 32 + 16 + ln]);

    for (int mt = 0; mt < 2; ++mt) {
      int lb = r0 + mt * 16 + ln;
      int lg2 = (bm & 15) * 128 + lb;
      f32x4 c2[2] = {};
      for (int kt = 0; kt < 4; ++kt) {
        uint4 u = *(uint4*)&sh[lb * ESTR + kt * 32 + qd * 8];
        bf16* e8 = (bf16*)&u;
        int pbase = kt * 16 + qd * 4;
        uint2 cu = *(const uint2*)&small[SM_COS + (size_t)lg2 * 64 + pbase];
        uint2 su = *(const uint2*)&small[SM_SIN + (size_t)lg2 * 64 + pbase];
        const bf16* cp = (const bf16*)&cu;
        const bf16* sp = (const bf16*)&su;
        for (int j = 0; j < 4; ++j) {
          float cvv = __bfloat162float(cp[j]);
          float svv = __bfloat162float(sp[j]);
          float ev = __bfloat162float(e8[2 * j]);
          float ov = __bfloat162float(e8[2 * j + 1]);
          e8[2 * j] = __float2bfloat16(ev * cvv - ov * svv);
          e8[2 * j + 1] = __float2bfloat16(ev * svv + ov * cvv);
        }
        bf16x8 a = *(bf16x8*)&u;
        c2[0] = __builtin_amdgcn_mfma_f32_16x16x32_bf16(a, bfr2[0][kt], c2[0], 0, 0, 0);
        c2[1] = __builtin_amdgcn_mfma_f32_16x16x32_bf16(a, bfr2[1][kt], c2[1], 0, 0, 0);
      }
      int lgbase = (bm & 15) * 128 + r0 + mt * 16 + qd * 4;
      bf16* dst = (reg == 0) ? qc : kc;
      for (int nt = 0; nt < 2; ++nt)
        for (int r = 0; r < 4; ++r)
          dst[((size_t)bh * Lseq + lgbase + r) * 32 + nt * 16 + ln] =
              __float2bfloat16(c2[nt][r] + bc[nt]);
    }
  } else {
    // ---- V-fold path: vcT[(b*512+n)][l] = x @ W~vt^T + bvF ----
    bf16* lA = sh;
    bf16* lB = sh + 2048;  // 64*32 elements each
    int rem = id - 1024;
    int nb = rem & 7, bm = rem >> 3;
    int wm = (w >> 1) * 32, wn = (w & 1) * 32;

    f32x4 acc[2][2] = {};
    const bf16* Ab = A + (size_t)(bm * 64) * K;
    const bf16* Bb = Wvt + (size_t)(nb * 64) * K;

    int r = t >> 2, c = (t & 3) * 8;
    for (int kt = 0; kt < K; kt += 32) {
      GLDS16(&Ab[(size_t)r * K + kt + c], &lA[t * 8]);
      GLDS16(&Bb[(size_t)r * K + kt + c], &lB[t * 8]);
      __syncthreads();
      bf16x8 af[2], bfr[2];
      for (int i = 0; i < 2; ++i) af[i] = *(bf16x8*)&lA[(wm + i * 16 + ln) * 32 + qd * 8];
      for (int j = 0; j < 2; ++j) bfr[j] = *(bf16x8*)&lB[(wn + j * 16 + ln) * 32 + qd * 8];
      for (int i = 0; i < 2; ++i)
        for (int j = 0; j < 2; ++j)
          acc[i][j] = __builtin_amdgcn_mfma_f32_16x16x32_bf16(af[i], bfr[j], acc[i][j], 0, 0, 0);
      __syncthreads();
    }

    int b = bm >> 5;
    for (int j = 0; j < 2; ++j) {
      int n = nb * 64 + wn + j * 16 + ln;
      float bb = bvF[n];
      for (int i = 0; i < 2; ++i) {
        int lloc = (bm & 31) * 64 + wm + i * 16 + qd * 4;
        bf16 p4[4] __attribute__((aligned(8)));
        for (int rr = 0; rr < 4; ++rr) p4[rr] = __float2bfloat16(acc[i][j][rr] + bb);
        *(uint2*)&vcT[((size_t)(b * 512 + n)) * 2048 + lloc] = *(uint2*)p4;
      }
    }
  }
}

// ---------------- output GEMM: d_out = attn @ Wot^T + boF (fp32 bias), K=512 ----------------
__global__ __launch_bounds__(256) void gemm_bias_out(const bf16* __restrict__ A,
                                                     const bf16* __restrict__ Bt,
                                                     const float* __restrict__ bias,
                                                     void* __restrict__ C,
                                                     int M, int N, int K,
                                                     const int* __restrict__ flagp) {
  __shared__ bf16 lA[128 * 32];
  __shared__ bf16 lB[128 * 32];
  int f32out = *flagp;
  int bm = blockIdx.y, bn = blockIdx.x;
  int t = threadIdx.x;
  int lane = t & 63, w = t >> 6;
  int wm = (w >> 1) * 64, wn = (w & 1) * 64;
  int qd = lane >> 4, ln = lane & 15;

  f32x4 acc[4][4] = {};
  const bf16* Ab = A + (size_t)(bm * 128) * K;
  const bf16* Bb = Bt + (size_t)(bn * 128) * K;

  for (int kt = 0; kt < K; kt += 32) {
    for (int p = 0; p < 2; ++p) {
      int slot = t + p * 256;
      int r = slot >> 2, c = (slot & 3) * 8;
      GLDS16(&Ab[(size_t)r * K + kt + c], &lA[slot * 8]);
      GLDS16(&Bb[(size_t)r * K + kt + c], &lB[slot * 8]);
    }
    __syncthreads();
    bf16x8 af[4], bfr[4];
    for (int i = 0; i < 4; ++i) af[i] = *(bf16x8*)&lA[(wm + i * 16 + ln) * 32 + qd * 8];
    for (int j = 0; j < 4; ++j) bfr[j] = *(bf16x8*)&lB[(wn + j * 16 + ln) * 32 + qd * 8];
    for (int i = 0; i < 4; ++i)
      for (int j = 0; j < 4; ++j)
        acc[i][j] = __builtin_amdgcn_mfma_f32_16x16x32_bf16(af[i], bfr[j], acc[i][j], 0, 0, 0);
    __syncthreads();
  }
  for (int i = 0; i < 4; ++i)
    for (int j = 0; j < 4; ++j) {
      int col = bn * 128 + wn + j * 16 + ln;
      float bv = bias[col];
      for (int r = 0; r < 4; ++r) {
        int row = bm * 128 + wm + i * 16 + qd * 4 + r;
        float v = acc[i][j][r] + bv;
        if (f32out) ((float*)C)[(size_t)row * N + col] = v;
        else ((bf16*)C)[(size_t)row * N + col] = __float2bfloat16(v);
      }
    }
}

// ---------------- flash attention R10: prefetched loads, exp2-domain softmax ----------------
__global__ __launch_bounds__(256) void flash32(const bf16* __restrict__ qc,
                                               const bf16* __restrict__ kc,
                                               const bf16* __restrict__ vcT,
                                               bf16* __restrict__ attn) {
  __shared__ bf16 pbuf[4][16 * 72];     // 9216 B
  __shared__ float oL[4][16][33];       // 8448 B
  __shared__ float mL[4][16];
  __shared__ float lsL[4][16];
  int t = threadIdx.x;
  int lane = t & 63, w = t >> 6;
  int qd = lane >> 4, ln = lane & 15;
  int blk = blockIdx.x;                 // grid 4096 = 32 bh x 128 q-tiles
  int j = blk & 127;
  int bh = blk >> 7, h = bh & 15, b = bh >> 4;
  int q0 = j * 16;

  bf16x8 qf = *(const bf16x8*)&qc[((size_t)bh * Lseq + q0 + ln) * 32 + qd * 8];

  f32x4 o0 = {}, o1 = {};
  float m[4], ls[4];
  for (int r = 0; r < 4; ++r) { m[r] = -1e30f; ls[r] = 0.f; }
  // log2-domain: fold log2(e) into the score scale
  const float scale2 = 0.17677669529663687f * 1.4426950408889634f;

  int n64 = (q0 + 16 + 63) >> 6;        // causal KV chunks of 64
  int nw = (n64 + 3) >> 2;
  int c0 = w * nw;
  int c1 = min(c0 + nw, n64);

  bf16* pb = pbuf[w];
  bf16x8 kf[4];
  if (c0 < c1) {
    int k0 = c0 * 64;
    for (int c = 0; c < 4; ++c)
      kf[c] = *(const bf16x8*)&kc[((size_t)bh * Lseq + k0 + c * 16 + ln) * 32 + qd * 8];
  }
  for (int ci = c0; ci < c1; ++ci) {
    int k0 = ci * 64;
    f32x4 s[4];
    for (int c = 0; c < 4; ++c) {
      f32x4 z = {};
      s[c] = __builtin_amdgcn_mfma_f32_16x16x32_bf16(qf, kf[c], z, 0, 0, 0);
    }
    // issue V(this chunk) + K(next chunk) loads BEFORE the softmax chain:
    // their ~L2/HBM latency hides under the shuffle/exp critical path.
    size_t vbase = ((size_t)bh * 32 + ln) * Lseq + k0 + qd * 8;
    bf16x8 vf00 = *(const bf16x8*)&vcT[vbase];
    bf16x8 vf01 = *(const bf16x8*)&vcT[vbase + 32];
    bf16x8 vf10 = *(const bf16x8*)&vcT[vbase + (size_t)16 * Lseq];
    bf16x8 vf11 = *(const bf16x8*)&vcT[vbase + (size_t)16 * Lseq + 32];
    if (ci + 1 < c1) {
      int k0n = k0 + 64;
      for (int c = 0; c < 4; ++c)
        kf[c] = *(const bf16x8*)&kc[((size_t)bh * Lseq + k0n + c * 16 + ln) * 32 + qd * 8];
    }
    float sv[4][4], alpha[4];
    for (int r = 0; r < 4; ++r) {
      int qrow = q0 + qd * 4 + r;
      for (int c = 0; c < 4; ++c)
        sv[c][r] = (k0 + c * 16 + ln <= qrow) ? s[c][r] * scale2 : -1e30f;
    }
    for (int r = 0; r < 4; ++r) {
      float mx = fmaxf(fmaxf(sv[0][r], sv[1][r]), fmaxf(sv[2][r], sv[3][r]));
      for (int off = 1; off < 16; off <<= 1) mx = fmaxf(mx, __shfl_xor(mx, off, 64));
      float mn = fmaxf(m[r], mx);
      alpha[r] = exp2f(m[r] - mn);
      m[r] = mn;
      float rs = 0.f;
      for (int c = 0; c < 4; ++c) { sv[c][r] = exp2f(sv[c][r] - mn); rs += sv[c][r]; }
      ls[r] = ls[r] * alpha[r] + rs;
      o0[r] *= alpha[r];
      o1[r] *= alpha[r];
    }
    for (int r = 0; r < 4; ++r)
      for (int c = 0; c < 4; ++c)
        pb[(qd * 4 + r) * 72 + c * 16 + ln] = __float2bfloat16(sv[c][r]);
    asm volatile("s_waitcnt lgkmcnt(0)" ::: "memory");
    bf16x8 pf0 = *(bf16x8*)&pb[ln * 72 + qd * 8];
    bf16x8 pf1 = *(bf16x8*)&pb[ln * 72 + 32 + qd * 8];
    o0 = __builtin_amdgcn_mfma_f32_16x16x32_bf16(pf0, vf00, o0, 0, 0, 0);
    o0 = __builtin_amdgcn_mfma_f32_16x16x32_bf16(pf1, vf01, o0, 0, 0, 0);
    o1 = __builtin_amdgcn_mfma_f32_16x16x32_bf16(pf0, vf10, o1, 0, 0, 0);
    o1 = __builtin_amdgcn_mfma_f32_16x16x32_bf16(pf1, vf11, o1, 0, 0, 0);
  }

  // one end reduce of the per-lane lsum partials
  for (int r = 0; r < 4; ++r)
    for (int off = 1; off < 16; off <<= 1) ls[r] += __shfl_xor(ls[r], off, 64);

  // write wave partials
  for (int r = 0; r < 4; ++r) {
    int row = qd * 4 + r;
    oL[w][row][ln] = o0[r];
    oL[w][row][16 + ln] = o1[r];
    if (ln == 0) { mL[w][row] = m[r]; lsL[w][row] = ls[r]; }
  }
  __syncthreads();

  // merge 4 wave-partials (flash-decode combine), log2-domain
  for (int idx = t; idx < 512; idx += 256) {
    int row = idx >> 5, col = idx & 31;
    float m0 = mL[0][row], m1 = mL[1][row], m2 = mL[2][row], m3 = mL[3][row];
    float ms = fmaxf(fmaxf(m0, m1), fmaxf(m2, m3));
    float e0 = exp2f(m0 - ms), e1 = exp2f(m1 - ms);
    float e2 = exp2f(m2 - ms), e3 = exp2f(m3 - ms);
    float lsum = lsL[0][row] * e0 + lsL[1][row] * e1 + lsL[2][row] * e2 + lsL[3][row] * e3;
    float val = oL[0][row][col] * e0 + oL[1][row][col] * e1 +
                oL[2][row][col] * e2 + oL[3][row][col] * e3;
    int l = q0 + row;
    attn[((size_t)(b * Lseq + l)) * 512 + h * 32 + col] = __float2bfloat16(val / lsum);
  }
}

extern "C" void kernel_launch(void* const* d_in, const int* in_sizes, int n_in,
                              void* d_out, int out_size, void* d_ws, size_t ws_size,
                              hipStream_t stream) {
  const void* x = d_in[0];
  const void* cosS = d_in[1];
  const void* sinS = d_in[2];
  const void* Wq = d_in[3];
  const void* bq = d_in[4];
  const void* Wk = d_in[5];
  const void* bk = d_in[6];
  const void* Wv = d_in[7];
  const void* bv = d_in[8];
  const void* Wqc = d_in[9];
  const void* bqc = d_in[10];
  const void* Wkc = d_in[11];
  const void* bkc = d_in[12];
  const void* Wvc = d_in[13];
  const void* bvc = d_in[14];
  const void* Wd = d_in[15];
  const void* bd = d_in[16];
  const void* Wo = d_in[17];
  const void* bo = d_in[18];

  char* ws = (char*)d_ws;
  size_t off = 0;
  auto alloc = [&](size_t bytes) {
    char* p = ws + off;
    off += (bytes + 255) & ~(size_t)255;
    return p;
  };
  int* flag = (int*)alloc(256);
  bf16* small = (bf16*)alloc((size_t)SM_TOT * 2);
  bf16* wctG = (bf16*)alloc((size_t)12288 * 2);
  bf16* wdtG = (bf16*)alloc((size_t)4096 * 2);
  bf16* xb = (bf16*)alloc((size_t)4096 * 2048 * 2);
  bf16* WvB = (bf16*)alloc((size_t)2048 * 2048 * 2);
  bf16* WtQK = (bf16*)alloc((size_t)4096 * 2048 * 2);
  bf16* WtO = (bf16*)alloc((size_t)2048 * 2048 * 2);
  bf16* Wvt = (bf16*)alloc((size_t)512 * 2048 * 2);
  bf16* Wot = (bf16*)alloc((size_t)2048 * 512 * 2);
  float* bo_part = (float*)alloc((size_t)16 * 2048 * 4);
  float* boF = (float*)alloc((size_t)2048 * 4);
  float* bvF = (float*)alloc((size_t)512 * 4);
  bf16* qcW = (bf16*)alloc((size_t)65536 * 32 * 2);
  bf16* kcW = (bf16*)alloc((size_t)65536 * 32 * 2);
  bf16* vcTW = (bf16*)alloc((size_t)65536 * 32 * 2);
  bf16* attnW = (bf16*)alloc((size_t)4096 * 512 * 2);

  dim3 tb(256);
  detect_dtype<<<1, 64, 0, stream>>>((const ushort*)x, flag);
  prep_all<<<NB_PREP_ALL, tb, 0, stream>>>(
      x, cosS, sinS, Wq, Wk, Wv, Wo, Wqc, Wkc, Wvc, bqc, bkc, bvc, Wd, bd, bo,
      bq, bk, bv, xb, WvB, WtQK, WtO, small, wctG, wdtG, bo_part, flag);
  fold_all<<<522, tb, 0, stream>>>(WvB, wctG, WtO, small, bo, bo_part, bv, bvc,
                                   Wvc, Wvt, Wot, boF, bvF, flag);
  gemm_qkv<<<1536, tb, 0, stream>>>(xb, WtQK, Wvt, small, wctG, bvF, qcW, kcW, vcTW);
  flash32<<<4096, tb, 0, stream>>>(qcW, kcW, vcTW, attnW);
  gemm_bias_out<<<dim3(16, 32), tb, 0, stream>>>(attnW, Wot, boF, d_out, 4096, 2048,
                                                 512, flag);
}